// Round 1
// baseline (2630.525 us; speedup 1.0000x reference)
//
#include <hip/hip_runtime.h>

#define NN 250000
#define EE 1000000
#define SS 1000
#define DD 64
#define FIN 16
#define FEE 8
#define NL 3

// ---------------- count nodes per segment ----------------
__global__ __launch_bounds__(256) void k_count(const int* __restrict__ nidx,
                                               float* __restrict__ cnt) {
  int i = blockIdx.x * 256 + threadIdx.x;
  if (i < NN) atomicAdd(&cnt[nidx[i]], 1.0f);
}

// ---------------- init encoder: h = x @ W_init + b ----------------
__global__ __launch_bounds__(256) void k_init(const float* __restrict__ x,
                                              const float* __restrict__ W,
                                              const float* __restrict__ b,
                                              float* __restrict__ h) {
  int gid = blockIdx.x * 256 + threadIdx.x;  // N*64 total, divisible by 256
  int n = gid >> 6, d = gid & 63;
  const float* xr = x + (size_t)n * FIN;
  float acc = b[d];
#pragma unroll
  for (int k = 0; k < FIN; k++) acc += xr[k] * W[k * DD + d];
  h[gid] = acc;
}

// ---------------- edge kernel: agg += relu(h[src] + ea@We + be) at dst ----------------
__global__ __launch_bounds__(256) void k_edge(const float* __restrict__ h,
                                              const float* __restrict__ ea,
                                              const int* __restrict__ src,
                                              const int* __restrict__ dst,
                                              const float* __restrict__ We,
                                              const float* __restrict__ be,
                                              float* __restrict__ agg) {
  __shared__ float sWe[FEE * DD];
  __shared__ float sbe[DD];
  int tid = threadIdx.x;
  for (int i = tid; i < FEE * DD; i += 256) sWe[i] = We[i];
  if (tid < DD) sbe[tid] = be[tid];
  __syncthreads();
  int e = blockIdx.x * 4 + (tid >> 6);
  int d = tid & 63;
  if (e >= EE) return;
  const float* ear = ea + (size_t)e * FEE;
  float emb = sbe[d];
#pragma unroll
  for (int k = 0; k < FEE; k++) emb += ear[k] * sWe[k * DD + d];
  int s = src[e], t = dst[e];
  float m = h[(size_t)s * DD + d] + emb;
  m = m > 0.0f ? m : 0.0f;
  atomicAdd(&agg[(size_t)t * DD + d], m);
}

// ---------------- segment sum of h ----------------
__global__ __launch_bounds__(256) void k_segsum(const float* __restrict__ h,
                                                const int* __restrict__ nidx,
                                                float* __restrict__ out) {
  int gid = blockIdx.x * 256 + threadIdx.x;  // N*64
  int n = gid >> 6, d = gid & 63;
  atomicAdd(&out[(size_t)nidx[n] * DD + d], h[gid]);
}

// ---------------- fused node kernel: 4 branches of MLP+LN, summed ----------------
struct NodeArgs {
  const float* h;
  const float* agg;
  const float* gsum;
  const float* cnt;
  const int* nidx;
  const int* root;
  const int* tr;
  const float* eps[4];
  const float* W1[4];
  const float* b1[4];
  const float* W2[4];
  const float* b2[4];
  const float* ga[4];
  const float* bb[4];
  float* hout;
};

__global__ __launch_bounds__(256) void k_node(NodeArgs A) {
  __shared__ float sO[64 * 65];   // u tile, [m][k] padded
  __shared__ float sUT[64 * 64];  // u transposed, [k][m]
  __shared__ float sT[64 * 65];   // t tile, [m][n] padded
  __shared__ float sW[64 * 64];   // current weight [k][n]
  __shared__ int sSeg[64];
  __shared__ int sRowV[64];
  __shared__ int sRowT[64];
  __shared__ float sInv[64];

  int tid = threadIdx.x;
  int m0 = blockIdx.x * 64;
  int ty = tid >> 4, tx = tid & 15;

  if (tid < 64) {
    int gm = m0 + tid;
    if (gm >= NN) gm = 0;
    int s = A.nidx[gm];
    sSeg[tid] = s;
    sRowV[tid] = A.root[s];
    sRowT[tid] = A.tr[gm];
    float c = A.cnt[s];
    if (c < 1.0f) c = 1.0f;
    sInv[tid] = 1.0f / c;
  }

  float hacc[4][4];
#pragma unroll
  for (int i = 0; i < 4; i++)
#pragma unroll
    for (int j = 0; j < 4; j++) hacc[i][j] = 0.0f;

  for (int b = 0; b < 4; b++) {
    float aeps = 1.0f + A.eps[b][0];
    __syncthreads();  // b=0: sSeg ready; b>0: prev GEMM2 done before sW/sT reuse

    // Phase A: sO[m][k] = aeps*h[m][k] + other[m][k]
    for (int idx = tid; idx < 64 * 16; idx += 256) {
      int m = idx >> 4, c4 = (idx & 15) * 4;
      int gm = m0 + m;
      if (gm >= NN) gm = 0;
      float4 hv = *(const float4*)&A.h[(size_t)gm * 64 + c4];
      float4 ov;
      if (b == 0) {
        ov = *(const float4*)&A.agg[(size_t)gm * 64 + c4];
      } else if (b == 1) {
        int r = sRowV[m];
        ov = *(const float4*)&A.h[(size_t)r * 64 + c4];
      } else if (b == 2) {
        int r = sRowT[m];
        ov = *(const float4*)&A.h[(size_t)r * 64 + c4];
      } else {
        int s = sSeg[m];
        float iv = sInv[m];
        float4 gv = *(const float4*)&A.gsum[s * 64 + c4];
        ov = make_float4(gv.x * iv, gv.y * iv, gv.z * iv, gv.w * iv);
      }
      float* p = &sO[m * 65 + c4];
      p[0] = aeps * hv.x + ov.x;
      p[1] = aeps * hv.y + ov.y;
      p[2] = aeps * hv.z + ov.z;
      p[3] = aeps * hv.w + ov.w;
    }
    __syncthreads();

    // Phase B: transpose u into sUT; stage W1
    for (int idx = tid; idx < 4096; idx += 256) {
      int m = idx & 63, k = idx >> 6;
      sUT[k * 64 + m] = sO[m * 65 + k];
    }
    {
      const float* w1 = A.W1[b];
      for (int idx = tid; idx < 4096; idx += 256) sW[idx] = w1[idx];
    }
    __syncthreads();

    // GEMM1: t = relu(u @ W1 + b1)
    float acc[4][4];
    {
      const float* b1 = A.b1[b];
      float b1v[4];
#pragma unroll
      for (int j = 0; j < 4; j++) b1v[j] = b1[tx * 4 + j];
#pragma unroll
      for (int i = 0; i < 4; i++)
#pragma unroll
        for (int j = 0; j < 4; j++) acc[i][j] = b1v[j];
    }
#pragma unroll 8
    for (int k = 0; k < 64; k++) {
      float4 wv = *(const float4*)&sW[k * 64 + tx * 4];
      float4 uv = *(const float4*)&sUT[k * 64 + ty * 4];
      acc[0][0] += uv.x * wv.x; acc[0][1] += uv.x * wv.y; acc[0][2] += uv.x * wv.z; acc[0][3] += uv.x * wv.w;
      acc[1][0] += uv.y * wv.x; acc[1][1] += uv.y * wv.y; acc[1][2] += uv.y * wv.z; acc[1][3] += uv.y * wv.w;
      acc[2][0] += uv.z * wv.x; acc[2][1] += uv.z * wv.y; acc[2][2] += uv.z * wv.z; acc[2][3] += uv.z * wv.w;
      acc[3][0] += uv.w * wv.x; acc[3][1] += uv.w * wv.y; acc[3][2] += uv.w * wv.z; acc[3][3] += uv.w * wv.w;
    }
#pragma unroll
    for (int i = 0; i < 4; i++)
#pragma unroll
      for (int j = 0; j < 4; j++) {
        float v = acc[i][j];
        sT[(ty * 4 + i) * 65 + tx * 4 + j] = v > 0.0f ? v : 0.0f;
      }
    __syncthreads();

    // stage W2
    {
      const float* w2 = A.W2[b];
      for (int idx = tid; idx < 4096; idx += 256) sW[idx] = w2[idx];
    }
    __syncthreads();

    // GEMM2: v = t @ W2 + b2
    float acc2[4][4];
    {
      const float* b2 = A.b2[b];
      float b2v[4];
#pragma unroll
      for (int j = 0; j < 4; j++) b2v[j] = b2[tx * 4 + j];
#pragma unroll
      for (int i = 0; i < 4; i++)
#pragma unroll
        for (int j = 0; j < 4; j++) acc2[i][j] = b2v[j];
    }
#pragma unroll 8
    for (int k = 0; k < 64; k++) {
      float4 wv = *(const float4*)&sW[k * 64 + tx * 4];
      float t0 = sT[(ty * 4 + 0) * 65 + k];
      float t1 = sT[(ty * 4 + 1) * 65 + k];
      float t2 = sT[(ty * 4 + 2) * 65 + k];
      float t3 = sT[(ty * 4 + 3) * 65 + k];
      acc2[0][0] += t0 * wv.x; acc2[0][1] += t0 * wv.y; acc2[0][2] += t0 * wv.z; acc2[0][3] += t0 * wv.w;
      acc2[1][0] += t1 * wv.x; acc2[1][1] += t1 * wv.y; acc2[1][2] += t1 * wv.z; acc2[1][3] += t1 * wv.w;
      acc2[2][0] += t2 * wv.x; acc2[2][1] += t2 * wv.y; acc2[2][2] += t2 * wv.z; acc2[2][3] += t2 * wv.w;
      acc2[3][0] += t3 * wv.x; acc2[3][1] += t3 * wv.y; acc2[3][2] += t3 * wv.z; acc2[3][3] += t3 * wv.w;
    }

    // LayerNorm per row (row = 16 consecutive lanes), then accumulate
    const float* ga = A.ga[b];
    const float* bbp = A.bb[b];
    float gav[4], bbv[4];
#pragma unroll
    for (int j = 0; j < 4; j++) {
      gav[j] = ga[tx * 4 + j];
      bbv[j] = bbp[tx * 4 + j];
    }
#pragma unroll
    for (int i = 0; i < 4; i++) {
      float s1 = acc2[i][0] + acc2[i][1] + acc2[i][2] + acc2[i][3];
      float s2 = acc2[i][0] * acc2[i][0] + acc2[i][1] * acc2[i][1] +
                 acc2[i][2] * acc2[i][2] + acc2[i][3] * acc2[i][3];
#pragma unroll
      for (int o = 1; o < 16; o <<= 1) {
        s1 += __shfl_xor(s1, o);
        s2 += __shfl_xor(s2, o);
      }
      float mu = s1 * (1.0f / 64.0f);
      float var = s2 * (1.0f / 64.0f) - mu * mu;
      float r = rsqrtf(var + 1e-5f);
#pragma unroll
      for (int j = 0; j < 4; j++)
        hacc[i][j] += (acc2[i][j] - mu) * r * gav[j] + bbv[j];
    }
  }

  // write h_new tile
#pragma unroll
  for (int i = 0; i < 4; i++) {
    int gm = m0 + ty * 4 + i;
    if (gm < NN) {
      float4 v = make_float4(hacc[i][0], hacc[i][1], hacc[i][2], hacc[i][3]);
      *(float4*)&A.hout[(size_t)gm * 64 + tx * 4] = v;
    }
  }
}

// ---------------- decoder: out = pooled @ W_jk + b_jk ----------------
__global__ __launch_bounds__(256) void k_out(const float* __restrict__ pooled,
                                             const float* __restrict__ W,
                                             const float* __restrict__ b,
                                             float* __restrict__ out) {
  int gid = blockIdx.x * 256 + threadIdx.x;  // S*64
  if (gid >= SS * DD) return;
  int s = gid >> 6, d = gid & 63;
  const float* pr = pooled + (size_t)s * DD;
  float acc = b[d];
#pragma unroll
  for (int k = 0; k < DD; k++) acc += pr[k] * W[k * DD + d];
  out[gid] = acc;
}

extern "C" void kernel_launch(void* const* d_in, const int* in_sizes, int n_in,
                              void* d_out, int out_size, void* d_ws, size_t ws_size,
                              hipStream_t stream) {
  const float* x = (const float*)d_in[0];
  const float* edge_attr = (const float*)d_in[1];
  const int* edge_index = (const int*)d_in[2];
  const int* node_idx = (const int*)d_in[3];
  const int* root_idx = (const int*)d_in[4];
  const int* transpose_idx = (const int*)d_in[5];
  const float* W_init = (const float*)d_in[6];
  const float* b_init = (const float*)d_in[7];
  // branch order: lu(8..16), vv(17..23), vu(24..30), gl(31..37)
  const float* lu_We = (const float*)d_in[8];
  const float* lu_be = (const float*)d_in[9];
  const float* eps_[4] = {(const float*)d_in[10], (const float*)d_in[17],
                          (const float*)d_in[24], (const float*)d_in[31]};
  const float* W1_[4] = {(const float*)d_in[11], (const float*)d_in[18],
                         (const float*)d_in[25], (const float*)d_in[32]};
  const float* b1_[4] = {(const float*)d_in[12], (const float*)d_in[19],
                         (const float*)d_in[26], (const float*)d_in[33]};
  const float* W2_[4] = {(const float*)d_in[13], (const float*)d_in[20],
                         (const float*)d_in[27], (const float*)d_in[34]};
  const float* b2_[4] = {(const float*)d_in[14], (const float*)d_in[21],
                         (const float*)d_in[28], (const float*)d_in[35]};
  const float* ga_[4] = {(const float*)d_in[15], (const float*)d_in[22],
                         (const float*)d_in[29], (const float*)d_in[36]};
  const float* bn_[4] = {(const float*)d_in[16], (const float*)d_in[23],
                         (const float*)d_in[30], (const float*)d_in[37]};
  const float* W_jk = (const float*)d_in[38];
  const float* b_jk = (const float*)d_in[39];

  float* ws = (float*)d_ws;
  float* h0 = ws;                      // N*D
  float* h1 = h0 + (size_t)NN * DD;    // N*D
  float* agg = h1 + (size_t)NN * DD;   // N*D
  float* gsum = agg + (size_t)NN * DD; // S*D
  float* cnt = gsum + SS * DD;         // S
  float* pooled = cnt + SS;            // S*D

  hipMemsetAsync(cnt, 0, SS * sizeof(float), stream);
  hipMemsetAsync(pooled, 0, SS * DD * sizeof(float), stream);
  k_count<<<(NN + 255) / 256, 256, 0, stream>>>(node_idx, cnt);
  k_init<<<(NN * DD) / 256, 256, 0, stream>>>(x, W_init, b_init, h0);

  float* hc = h0;
  float* hn = h1;
  for (int l = 0; l < NL; l++) {
    hipMemsetAsync(agg, 0, (size_t)NN * DD * sizeof(float), stream);
    hipMemsetAsync(gsum, 0, SS * DD * sizeof(float), stream);
    k_edge<<<(EE + 3) / 4, 256, 0, stream>>>(hc, edge_attr, edge_index, edge_index + EE,
                                             lu_We + (size_t)l * FEE * DD, lu_be + l * DD, agg);
    k_segsum<<<(NN * DD) / 256, 256, 0, stream>>>(hc, node_idx, gsum);

    NodeArgs A;
    A.h = hc; A.agg = agg; A.gsum = gsum; A.cnt = cnt;
    A.nidx = node_idx; A.root = root_idx; A.tr = transpose_idx;
    for (int b = 0; b < 4; b++) {
      A.eps[b] = eps_[b] + l;
      A.W1[b] = W1_[b] + (size_t)l * DD * DD;
      A.b1[b] = b1_[b] + l * DD;
      A.W2[b] = W2_[b] + (size_t)l * DD * DD;
      A.b2[b] = b2_[b] + l * DD;
      A.ga[b] = ga_[b] + l * DD;
      A.bb[b] = bn_[b] + l * DD;
    }
    A.hout = hn;
    k_node<<<(NN + 63) / 64, 256, 0, stream>>>(A);
    float* tmp = hc; hc = hn; hn = tmp;
  }

  k_segsum<<<(NN * DD) / 256, 256, 0, stream>>>(hc, node_idx, pooled);
  k_out<<<(SS * DD + 255) / 256, 256, 0, stream>>>(pooled, W_jk, b_jk, (float*)d_out);
}

// Round 2
// 1890.332 us; speedup vs baseline: 1.3916x; 1.3916x over previous
//
#include <hip/hip_runtime.h>

#define NN 250000
#define EE 1000000
#define SS 1000
#define DD 64
#define FIN 16
#define FEE 8
#define NL 3
#define LDH 72  // LDS row stride in bf16 elems: 144 B -> bank shift 4/row (2-way max, free)

typedef __attribute__((ext_vector_type(8))) short bf16x8;
typedef __attribute__((ext_vector_type(4))) float f32x4;

static __device__ __forceinline__ short f2bf(float f) {
  union { float f; unsigned u; } v{f};
  unsigned r = (v.u + 0x7fffu + ((v.u >> 16) & 1u)) >> 16;  // RNE
  return (short)r;
}

// ---------------- count nodes per segment ----------------
__global__ __launch_bounds__(256) void k_count(const int* __restrict__ nidx,
                                               float* __restrict__ cnt) {
  int i = blockIdx.x * 256 + threadIdx.x;
  if (i < NN) atomicAdd(&cnt[nidx[i]], 1.0f);
}

// ---------------- init encoder: h = x @ W_init + b ----------------
__global__ __launch_bounds__(256) void k_init(const float* __restrict__ x,
                                              const float* __restrict__ W,
                                              const float* __restrict__ b,
                                              float* __restrict__ h) {
  int gid = blockIdx.x * 256 + threadIdx.x;
  int n = gid >> 6, d = gid & 63;
  const float* xr = x + (size_t)n * FIN;
  float acc = b[d];
#pragma unroll
  for (int k = 0; k < FIN; k++) acc += xr[k] * W[k * DD + d];
  h[gid] = acc;
}

// ---------------- weight prep: bf16 W^T for all 4 branches x {W1,W2} x L ----------------
struct WPrep { const float* W[8]; };  // [b*2+g], each L*64*64 fp32, [l][k][n]

__global__ __launch_bounds__(256) void k_wprep(WPrep P, short* __restrict__ wbt) {
  int gid = blockIdx.x * 256 + threadIdx.x;  // 24*4096
  int slot = gid >> 12;                      // (b*2+g)*NL + l
  int e = gid & 4095;
  int n = e >> 6, k = e & 63;
  int bg = slot / NL, l = slot % NL;
  float v = P.W[bg][(size_t)l * 4096 + k * 64 + n];  // W[k][n] -> Wt[n][k]
  wbt[gid] = f2bf(v);
}

// ---------------- edge kernel: agg += relu(h[src] + ea@We + be) at dst ----------------
__global__ __launch_bounds__(256) void k_edge(const float* __restrict__ h,
                                              const float* __restrict__ ea,
                                              const int* __restrict__ src,
                                              const int* __restrict__ dst,
                                              const float* __restrict__ We,
                                              const float* __restrict__ be,
                                              float* __restrict__ agg) {
  __shared__ float sWe[FEE * DD];
  __shared__ float sbe[DD];
  int tid = threadIdx.x;
  for (int i = tid; i < FEE * DD; i += 256) sWe[i] = We[i];
  if (tid < DD) sbe[tid] = be[tid];
  __syncthreads();
  int e = blockIdx.x * 4 + (tid >> 6);
  int d = tid & 63;
  if (e >= EE) return;
  const float* ear = ea + (size_t)e * FEE;
  float emb = sbe[d];
#pragma unroll
  for (int k = 0; k < FEE; k++) emb += ear[k] * sWe[k * DD + d];
  int s = src[e], t = dst[e];
  float m = h[(size_t)s * DD + d] + emb;
  m = m > 0.0f ? m : 0.0f;
  atomicAdd(&agg[(size_t)t * DD + d], m);
}

// ---------------- segment sum of h ----------------
__global__ __launch_bounds__(256) void k_segsum(const float* __restrict__ h,
                                                const int* __restrict__ nidx,
                                                float* __restrict__ out) {
  int gid = blockIdx.x * 256 + threadIdx.x;  // N*64
  int n = gid >> 6, d = gid & 63;
  atomicAdd(&out[(size_t)nidx[n] * DD + d], h[gid]);
}

// ---------------- fused node kernel (MFMA): 4 branches of MLP+LN, summed ----------------
struct NodeArgs {
  const float* h;
  const float* agg;
  const float* gsum;
  const float* cnt;
  const int* nidx;
  const int* root;
  const int* tr;
  const float* eps[4];
  const short* wt1[4];  // bf16 W1^T [n][k]
  const short* wt2[4];  // bf16 W2^T [n][k]
  const float* b1[4];
  const float* b2[4];
  const float* ga[4];
  const float* bb[4];
  float* hout;
};

__global__ __launch_bounds__(256) void k_node(NodeArgs A) {
  __shared__ short sU[64 * LDH];  // u tile bf16, [m][k]
  __shared__ short sT[64 * LDH];  // relu(GEMM1) bf16, [m][k]
  __shared__ int sSeg[64];
  __shared__ int sRowV[64];
  __shared__ int sRowT[64];
  __shared__ float sInv[64];

  int tid = threadIdx.x;
  int m0 = blockIdx.x * 64;
  int wv = tid >> 6;    // wave 0..3, owns rows [wv*16, wv*16+16)
  int lane = tid & 63;
  int col = lane & 15;  // MFMA m/n index
  int quad = lane >> 4; // MFMA k-group / row-group

  if (tid < 64) {
    int gm = m0 + tid;
    if (gm >= NN) gm = 0;
    int s = A.nidx[gm];
    sSeg[tid] = s;
    sRowV[tid] = A.root[s];
    sRowT[tid] = A.tr[gm];
    float c = A.cnt[s];
    if (c < 1.0f) c = 1.0f;
    sInv[tid] = 1.0f / c;
  }

  float hacc[4][4];  // [reg(row)][tile(n)]
#pragma unroll
  for (int i = 0; i < 4; i++)
#pragma unroll
    for (int j = 0; j < 4; j++) hacc[i][j] = 0.0f;

  int arow = wv * 16 + col;  // A-fragment row (m = lane&15 within band)

  for (int b = 0; b < 4; b++) {
    float aeps = 1.0f + A.eps[b][0];
    __syncthreads();  // b=0: sSeg ready; b>0: prior A-frag reads of sU done

    // Phase A: sU[m][k] = bf16(aeps*h[m][k] + other[m][k])
    for (int idx = tid; idx < 64 * 16; idx += 256) {
      int m = idx >> 4, c4 = (idx & 15) * 4;
      int gm = m0 + m;
      if (gm >= NN) gm = 0;
      float4 hv = *(const float4*)&A.h[(size_t)gm * 64 + c4];
      float4 ov;
      if (b == 0) {
        ov = *(const float4*)&A.agg[(size_t)gm * 64 + c4];
      } else if (b == 1) {
        int r = sRowV[m];
        ov = *(const float4*)&A.h[(size_t)r * 64 + c4];
      } else if (b == 2) {
        int r = sRowT[m];
        ov = *(const float4*)&A.h[(size_t)r * 64 + c4];
      } else {
        int s = sSeg[m];
        float iv = sInv[m];
        float4 gv = *(const float4*)&A.gsum[s * 64 + c4];
        ov = make_float4(gv.x * iv, gv.y * iv, gv.z * iv, gv.w * iv);
      }
      unsigned p0 = (unsigned short)f2bf(aeps * hv.x + ov.x) |
                    ((unsigned)(unsigned short)f2bf(aeps * hv.y + ov.y) << 16);
      unsigned p1 = (unsigned short)f2bf(aeps * hv.z + ov.z) |
                    ((unsigned)(unsigned short)f2bf(aeps * hv.w + ov.w) << 16);
      *(uint2*)&sU[m * LDH + c4] = make_uint2(p0, p1);
    }
    __syncthreads();

    const short* w1 = A.wt1[b];
    const short* w2 = A.wt2[b];
    const float* b1p = A.b1[b];
    const float* b2p = A.b2[b];

    // A-frags: m = arow, k = quad*8+j (+32 for second k-step)
    bf16x8 a0 = *(const bf16x8*)&sU[arow * LDH + quad * 8];
    bf16x8 a1 = *(const bf16x8*)&sU[arow * LDH + 32 + quad * 8];

    // GEMM1: T = relu(U @ W1 + b1), write bf16 into sT (wave-internal band)
#pragma unroll
    for (int t = 0; t < 4; t++) {
      int n = t * 16 + col;
      bf16x8 w0 = *(const bf16x8*)&w1[n * 64 + quad * 8];
      bf16x8 wk = *(const bf16x8*)&w1[n * 64 + 32 + quad * 8];
      float bv = b1p[n];
      f32x4 c = {bv, bv, bv, bv};
      c = __builtin_amdgcn_mfma_f32_16x16x32_bf16(a0, w0, c, 0, 0, 0);
      c = __builtin_amdgcn_mfma_f32_16x16x32_bf16(a1, wk, c, 0, 0, 0);
#pragma unroll
      for (int r = 0; r < 4; r++) {
        float v = c[r];
        v = v > 0.0f ? v : 0.0f;
        sT[(wv * 16 + quad * 4 + r) * LDH + n] = f2bf(v);  // C/D: row=quad*4+r, col=n
      }
    }
    // wave-internal LDS write->read: compiler lgkmcnt ordering suffices (same band)

    bf16x8 t0 = *(const bf16x8*)&sT[arow * LDH + quad * 8];
    bf16x8 t1 = *(const bf16x8*)&sT[arow * LDH + 32 + quad * 8];

    // GEMM2: V = T @ W2 + b2
    f32x4 c2[4];
#pragma unroll
    for (int t = 0; t < 4; t++) {
      int n = t * 16 + col;
      bf16x8 w0 = *(const bf16x8*)&w2[n * 64 + quad * 8];
      bf16x8 wk = *(const bf16x8*)&w2[n * 64 + 32 + quad * 8];
      float bv = b2p[n];
      f32x4 c = {bv, bv, bv, bv};
      c = __builtin_amdgcn_mfma_f32_16x16x32_bf16(t0, w0, c, 0, 0, 0);
      c = __builtin_amdgcn_mfma_f32_16x16x32_bf16(t1, wk, c, 0, 0, 0);
      c2[t] = c;
    }

    // LayerNorm per row (row = wv*16+quad*4+r; 16 lanes of this quad hold all 64 cols)
    const float* ga = A.ga[b];
    const float* bbp = A.bb[b];
    float gav[4], bbv[4];
#pragma unroll
    for (int t = 0; t < 4; t++) {
      gav[t] = ga[t * 16 + col];
      bbv[t] = bbp[t * 16 + col];
    }
#pragma unroll
    for (int r = 0; r < 4; r++) {
      float s1 = c2[0][r] + c2[1][r] + c2[2][r] + c2[3][r];
      float s2 = c2[0][r] * c2[0][r] + c2[1][r] * c2[1][r] +
                 c2[2][r] * c2[2][r] + c2[3][r] * c2[3][r];
#pragma unroll
      for (int o = 1; o < 16; o <<= 1) {
        s1 += __shfl_xor(s1, o);
        s2 += __shfl_xor(s2, o);
      }
      float mu = s1 * (1.0f / 64.0f);
      float var = s2 * (1.0f / 64.0f) - mu * mu;
      float rr = rsqrtf(var + 1e-5f);
#pragma unroll
      for (int t = 0; t < 4; t++)
        hacc[r][t] += (c2[t][r] - mu) * rr * gav[t] + bbv[t];
    }
  }

  // write h_new tile (fp32)
#pragma unroll
  for (int r = 0; r < 4; r++) {
    int gm = m0 + wv * 16 + quad * 4 + r;
    if (gm < NN) {
#pragma unroll
      for (int t = 0; t < 4; t++)
        A.hout[(size_t)gm * 64 + t * 16 + col] = hacc[r][t];
    }
  }
}

// ---------------- decoder: out = pooled @ W_jk + b_jk ----------------
__global__ __launch_bounds__(256) void k_out(const float* __restrict__ pooled,
                                             const float* __restrict__ W,
                                             const float* __restrict__ b,
                                             float* __restrict__ out) {
  int gid = blockIdx.x * 256 + threadIdx.x;
  if (gid >= SS * DD) return;
  int s = gid >> 6, d = gid & 63;
  const float* pr = pooled + (size_t)s * DD;
  float acc = b[d];
#pragma unroll
  for (int k = 0; k < DD; k++) acc += pr[k] * W[k * DD + d];
  out[gid] = acc;
}

extern "C" void kernel_launch(void* const* d_in, const int* in_sizes, int n_in,
                              void* d_out, int out_size, void* d_ws, size_t ws_size,
                              hipStream_t stream) {
  const float* x = (const float*)d_in[0];
  const float* edge_attr = (const float*)d_in[1];
  const int* edge_index = (const int*)d_in[2];
  const int* node_idx = (const int*)d_in[3];
  const int* root_idx = (const int*)d_in[4];
  const int* transpose_idx = (const int*)d_in[5];
  const float* x_W_init = (const float*)d_in[6];
  const float* b_init = (const float*)d_in[7];
  const float* lu_We = (const float*)d_in[8];
  const float* lu_be = (const float*)d_in[9];
  const float* eps_[4] = {(const float*)d_in[10], (const float*)d_in[17],
                          (const float*)d_in[24], (const float*)d_in[31]};
  const float* W1_[4] = {(const float*)d_in[11], (const float*)d_in[18],
                         (const float*)d_in[25], (const float*)d_in[32]};
  const float* b1_[4] = {(const float*)d_in[12], (const float*)d_in[19],
                         (const float*)d_in[26], (const float*)d_in[33]};
  const float* W2_[4] = {(const float*)d_in[13], (const float*)d_in[20],
                         (const float*)d_in[27], (const float*)d_in[34]};
  const float* b2_[4] = {(const float*)d_in[14], (const float*)d_in[21],
                         (const float*)d_in[28], (const float*)d_in[35]};
  const float* ga_[4] = {(const float*)d_in[15], (const float*)d_in[22],
                         (const float*)d_in[29], (const float*)d_in[36]};
  const float* bn_[4] = {(const float*)d_in[16], (const float*)d_in[23],
                         (const float*)d_in[30], (const float*)d_in[37]};
  const float* W_jk = (const float*)d_in[38];
  const float* b_jk = (const float*)d_in[39];

  float* ws = (float*)d_ws;
  float* h0 = ws;                        // N*D
  float* h1 = h0 + (size_t)NN * DD;      // N*D
  float* agg = h1 + (size_t)NN * DD;     // N*D
  float* gsum = agg + (size_t)NN * DD;   // S*D
  float* cnt = gsum + SS * DD;           // S
  float* pooled = cnt + SS;              // S*D
  short* wbt = (short*)(pooled + SS * DD);  // 24*4096 bf16

  hipMemsetAsync(cnt, 0, SS * sizeof(float), stream);
  hipMemsetAsync(pooled, 0, SS * DD * sizeof(float), stream);
  k_count<<<(NN + 255) / 256, 256, 0, stream>>>(node_idx, cnt);
  k_init<<<(NN * DD) / 256, 256, 0, stream>>>(x, x_W_init, b_init, h0);

  WPrep P;
  for (int b = 0; b < 4; b++) {
    P.W[b * 2 + 0] = W1_[b];
    P.W[b * 2 + 1] = W2_[b];
  }
  k_wprep<<<(24 * 4096) / 256, 256, 0, stream>>>(P, wbt);

  float* hc = h0;
  float* hn = h1;
  for (int l = 0; l < NL; l++) {
    hipMemsetAsync(agg, 0, (size_t)NN * DD * sizeof(float), stream);
    hipMemsetAsync(gsum, 0, SS * DD * sizeof(float), stream);
    k_edge<<<(EE + 3) / 4, 256, 0, stream>>>(hc, edge_attr, edge_index, edge_index + EE,
                                             lu_We + (size_t)l * FEE * DD, lu_be + l * DD, agg);
    k_segsum<<<(NN * DD) / 256, 256, 0, stream>>>(hc, node_idx, gsum);

    NodeArgs A;
    A.h = hc; A.agg = agg; A.gsum = gsum; A.cnt = cnt;
    A.nidx = node_idx; A.root = root_idx; A.tr = transpose_idx;
    for (int b = 0; b < 4; b++) {
      A.eps[b] = eps_[b] + l;
      A.wt1[b] = wbt + ((size_t)(b * 2 + 0) * NL + l) * 4096;
      A.wt2[b] = wbt + ((size_t)(b * 2 + 1) * NL + l) * 4096;
      A.b1[b] = b1_[b] + l * DD;
      A.b2[b] = b2_[b] + l * DD;
      A.ga[b] = ga_[b] + l * DD;
      A.bb[b] = bn_[b] + l * DD;
    }
    A.hout = hn;
    k_node<<<(NN + 63) / 64, 256, 0, stream>>>(A);
    float* tmp = hc; hc = hn; hn = tmp;
  }

  k_segsum<<<(NN * DD) / 256, 256, 0, stream>>>(hc, node_idx, pooled);
  k_out<<<(SS * DD + 255) / 256, 256, 0, stream>>>(pooled, W_jk, b_jk, (float*)d_out);
}

// Round 3
// 1536.523 us; speedup vs baseline: 1.7120x; 1.2303x over previous
//
#include <hip/hip_runtime.h>

#define NN 250000
#define EE 1000000
#define SS 1000
#define DD 64
#define FIN 16
#define FEE 8
#define NL 3
#define LDH 72  // LDS row stride in bf16 elems
#define SCHUNK 1024
#define SNB ((NN + SCHUNK - 1) / SCHUNK)  // 245

typedef __attribute__((ext_vector_type(8))) short bf16x8;
typedef __attribute__((ext_vector_type(4))) float f32x4;

static __device__ __forceinline__ short f2bf(float f) {
  union { float f; unsigned u; } v{f};
  unsigned r = (v.u + 0x7fffu + ((v.u >> 16) & 1u)) >> 16;  // RNE
  return (short)r;
}

// ---------------- histogram ----------------
__global__ __launch_bounds__(256) void k_hist(const int* __restrict__ idx,
                                              int* __restrict__ cnt, int n) {
  int i = blockIdx.x * 256 + threadIdx.x;
  if (i < n) atomicAdd(&cnt[idx[i]], 1);
}

// ---------------- block-local exclusive scan (chunk=1024) ----------------
__global__ __launch_bounds__(256) void k_scan1(const int* __restrict__ cntv,
                                               int* __restrict__ off,
                                               int* __restrict__ curs,
                                               int* __restrict__ bsums, int n) {
  __shared__ int ls[256];
  int b = blockIdx.x, t = threadIdx.x;
  int base = b * SCHUNK + t * 4;
  int v[4];
#pragma unroll
  for (int j = 0; j < 4; j++) v[j] = (base + j < n) ? cntv[base + j] : 0;
  int s4 = v[0] + v[1] + v[2] + v[3];
  ls[t] = s4;
  __syncthreads();
  for (int o = 1; o < 256; o <<= 1) {
    int x = (t >= o) ? ls[t - o] : 0;
    __syncthreads();
    ls[t] += x;
    __syncthreads();
  }
  int run = ls[t] - s4;
#pragma unroll
  for (int j = 0; j < 4; j++) {
    if (base + j < n) { off[base + j] = run; curs[base + j] = run; }
    run += v[j];
  }
  if (t == 255) bsums[b] = ls[255];
}

// scan the block sums (single block, n<=1024)
__global__ __launch_bounds__(256) void k_scan2(int* __restrict__ bsums, int nb) {
  __shared__ int ls[256];
  int t = threadIdx.x;
  // nb <= 256 assumed (245)
  int v = (t < nb) ? bsums[t] : 0;
  ls[t] = v;
  __syncthreads();
  for (int o = 1; o < 256; o <<= 1) {
    int x = (t >= o) ? ls[t - o] : 0;
    __syncthreads();
    ls[t] += x;
    __syncthreads();
  }
  if (t < nb) bsums[t] = ls[t] - v;  // exclusive
}

__global__ __launch_bounds__(256) void k_scan3(int* __restrict__ off,
                                               int* __restrict__ curs,
                                               const int* __restrict__ bsums, int n) {
  int b = blockIdx.x, t = threadIdx.x;
  int add = bsums[b];
  int base = b * SCHUNK + t * 4;
#pragma unroll
  for (int j = 0; j < 4; j++)
    if (base + j < n) { off[base + j] += add; curs[base + j] += add; }
}

// ---------------- bucket scatter ----------------
__global__ __launch_bounds__(256) void k_bucket_e(const int* __restrict__ src,
                                                  const int* __restrict__ dst,
                                                  int* __restrict__ curs,
                                                  int2* __restrict__ epk) {
  int e = blockIdx.x * 256 + threadIdx.x;
  if (e >= EE) return;
  int pos = atomicAdd(&curs[dst[e]], 1);
  epk[pos] = make_int2(src[e], e);
}

__global__ __launch_bounds__(256) void k_bucket_n(const int* __restrict__ nidx,
                                                  int* __restrict__ curs,
                                                  int* __restrict__ nsorted) {
  int n = blockIdx.x * 256 + threadIdx.x;
  if (n >= NN) return;
  int pos = atomicAdd(&curs[nidx[n]], 1);
  nsorted[pos] = n;
}

__global__ __launch_bounds__(256) void k_cntf(const int* __restrict__ ncnt,
                                              float* __restrict__ cnt) {
  int s = blockIdx.x * 256 + threadIdx.x;
  if (s < SS) {
    float c = (float)ncnt[s];
    cnt[s] = c < 1.0f ? 1.0f : c;
  }
}

// ---------------- init encoder: h = x @ W_init + b ----------------
__global__ __launch_bounds__(256) void k_init(const float* __restrict__ x,
                                              const float* __restrict__ W,
                                              const float* __restrict__ b,
                                              float* __restrict__ h) {
  int gid = blockIdx.x * 256 + threadIdx.x;
  int n = gid >> 6, d = gid & 63;
  const float* xr = x + (size_t)n * FIN;
  float acc = b[d];
#pragma unroll
  for (int k = 0; k < FIN; k++) acc += xr[k] * W[k * DD + d];
  h[gid] = acc;
}

// ---------------- weight prep: bf16 W^T ----------------
struct WPrep { const float* W[8]; };

__global__ __launch_bounds__(256) void k_wprep(WPrep P, short* __restrict__ wbt) {
  int gid = blockIdx.x * 256 + threadIdx.x;  // 24*4096
  int slot = gid >> 12;
  int e = gid & 4095;
  int n = e >> 6, k = e & 63;
  int bg = slot / NL, l = slot % NL;
  float v = P.W[bg][(size_t)l * 4096 + k * 64 + n];
  wbt[gid] = f2bf(v);
}

// ---------------- CSR edge aggregation: agg[v] = sum relu(h[src]+ea@We+be) ----------------
__global__ __launch_bounds__(256) void k_edge2(const float* __restrict__ h,
                                               const float* __restrict__ ea,
                                               const int2* __restrict__ epk,
                                               const int* __restrict__ eoff,
                                               const int* __restrict__ ecnt,
                                               const float* __restrict__ We,
                                               const float* __restrict__ be,
                                               float* __restrict__ agg) {
  int v = blockIdx.x * 4 + (threadIdx.x >> 6);
  int d = threadIdx.x & 63;
  if (v >= NN) return;
  float w[8];
#pragma unroll
  for (int k = 0; k < 8; k++) w[k] = We[k * 64 + d];
  float bed = be[d];
  int base = eoff[v], deg = ecnt[v];
  float acc = 0.0f;
  for (int i = 0; i < deg; i++) {
    int2 p = epk[base + i];
    const float* ear = ea + (size_t)p.y * 8;
    float4 e0 = *(const float4*)ear;
    float4 e1 = *(const float4*)(ear + 4);
    float emb = bed + e0.x * w[0] + e0.y * w[1] + e0.z * w[2] + e0.w * w[3] +
                e1.x * w[4] + e1.y * w[5] + e1.z * w[6] + e1.w * w[7];
    float m = h[(size_t)p.x * 64 + d] + emb;
    acc += m > 0.0f ? m : 0.0f;
  }
  agg[(size_t)v * 64 + d] = acc;
}

// ---------------- CSR segment sum: out[s] = sum_{n in seg s} h[n] ----------------
__global__ __launch_bounds__(256) void k_seg(const float* __restrict__ h,
                                             const int* __restrict__ nsorted,
                                             const int* __restrict__ noff,
                                             const int* __restrict__ ncnt,
                                             float* __restrict__ out) {
  __shared__ float red[256];
  int s = blockIdx.x;
  int t = threadIdx.x;
  int ch = t & 63, r = t >> 6;
  int base = noff[s], c = ncnt[s];
  float acc = 0.0f;
  for (int i = r; i < c; i += 4) {
    int n = nsorted[base + i];
    acc += h[(size_t)n * 64 + ch];
  }
  red[t] = acc;
  __syncthreads();
  if (r == 0)
    out[s * 64 + ch] = red[ch] + red[64 + ch] + red[128 + ch] + red[192 + ch];
}

// ---------------- fused node kernel (MFMA) ----------------
struct NodeArgs {
  const float* h;
  const float* agg;
  const float* gsum;
  const float* cnt;
  const int* nidx;
  const int* root;
  const int* tr;
  const float* eps[4];
  const short* wt1[4];
  const short* wt2[4];
  const float* b1[4];
  const float* b2[4];
  const float* ga[4];
  const float* bb[4];
  float* hout;
};

__global__ __launch_bounds__(256) void k_node(NodeArgs A) {
  __shared__ short sU[64 * LDH];
  __shared__ short sT[64 * LDH];
  __shared__ int sSeg[64];
  __shared__ int sRowV[64];
  __shared__ int sRowT[64];
  __shared__ float sInv[64];

  int tid = threadIdx.x;
  int m0 = blockIdx.x * 64;
  int wv = tid >> 6;
  int lane = tid & 63;
  int col = lane & 15;
  int quad = lane >> 4;

  if (tid < 64) {
    int gm = m0 + tid;
    if (gm >= NN) gm = 0;
    int s = A.nidx[gm];
    sSeg[tid] = s;
    sRowV[tid] = A.root[s];
    sRowT[tid] = A.tr[gm];
    float c = A.cnt[s];
    if (c < 1.0f) c = 1.0f;
    sInv[tid] = 1.0f / c;
  }

  float hacc[4][4];
#pragma unroll
  for (int i = 0; i < 4; i++)
#pragma unroll
    for (int j = 0; j < 4; j++) hacc[i][j] = 0.0f;

  int arow = wv * 16 + col;

  for (int b = 0; b < 4; b++) {
    float aeps = 1.0f + A.eps[b][0];
    __syncthreads();

    for (int idx = tid; idx < 64 * 16; idx += 256) {
      int m = idx >> 4, c4 = (idx & 15) * 4;
      int gm = m0 + m;
      if (gm >= NN) gm = 0;
      float4 hv = *(const float4*)&A.h[(size_t)gm * 64 + c4];
      float4 ov;
      if (b == 0) {
        ov = *(const float4*)&A.agg[(size_t)gm * 64 + c4];
      } else if (b == 1) {
        int r = sRowV[m];
        ov = *(const float4*)&A.h[(size_t)r * 64 + c4];
      } else if (b == 2) {
        int r = sRowT[m];
        ov = *(const float4*)&A.h[(size_t)r * 64 + c4];
      } else {
        int s = sSeg[m];
        float iv = sInv[m];
        float4 gv = *(const float4*)&A.gsum[s * 64 + c4];
        ov = make_float4(gv.x * iv, gv.y * iv, gv.z * iv, gv.w * iv);
      }
      unsigned p0 = (unsigned short)f2bf(aeps * hv.x + ov.x) |
                    ((unsigned)(unsigned short)f2bf(aeps * hv.y + ov.y) << 16);
      unsigned p1 = (unsigned short)f2bf(aeps * hv.z + ov.z) |
                    ((unsigned)(unsigned short)f2bf(aeps * hv.w + ov.w) << 16);
      *(uint2*)&sU[m * LDH + c4] = make_uint2(p0, p1);
    }
    __syncthreads();

    const short* w1 = A.wt1[b];
    const short* w2 = A.wt2[b];
    const float* b1p = A.b1[b];
    const float* b2p = A.b2[b];

    bf16x8 a0 = *(const bf16x8*)&sU[arow * LDH + quad * 8];
    bf16x8 a1 = *(const bf16x8*)&sU[arow * LDH + 32 + quad * 8];

#pragma unroll
    for (int t = 0; t < 4; t++) {
      int n = t * 16 + col;
      bf16x8 w0 = *(const bf16x8*)&w1[n * 64 + quad * 8];
      bf16x8 wk = *(const bf16x8*)&w1[n * 64 + 32 + quad * 8];
      float bv = b1p[n];
      f32x4 c = {bv, bv, bv, bv};
      c = __builtin_amdgcn_mfma_f32_16x16x32_bf16(a0, w0, c, 0, 0, 0);
      c = __builtin_amdgcn_mfma_f32_16x16x32_bf16(a1, wk, c, 0, 0, 0);
#pragma unroll
      for (int r = 0; r < 4; r++) {
        float v = c[r];
        v = v > 0.0f ? v : 0.0f;
        sT[(wv * 16 + quad * 4 + r) * LDH + n] = f2bf(v);
      }
    }

    bf16x8 t0 = *(const bf16x8*)&sT[arow * LDH + quad * 8];
    bf16x8 t1 = *(const bf16x8*)&sT[arow * LDH + 32 + quad * 8];

    f32x4 c2[4];
#pragma unroll
    for (int t = 0; t < 4; t++) {
      int n = t * 16 + col;
      bf16x8 w0 = *(const bf16x8*)&w2[n * 64 + quad * 8];
      bf16x8 wk = *(const bf16x8*)&w2[n * 64 + 32 + quad * 8];
      float bv = b2p[n];
      f32x4 c = {bv, bv, bv, bv};
      c = __builtin_amdgcn_mfma_f32_16x16x32_bf16(t0, w0, c, 0, 0, 0);
      c = __builtin_amdgcn_mfma_f32_16x16x32_bf16(t1, wk, c, 0, 0, 0);
      c2[t] = c;
    }

    const float* ga = A.ga[b];
    const float* bbp = A.bb[b];
    float gav[4], bbv[4];
#pragma unroll
    for (int t = 0; t < 4; t++) {
      gav[t] = ga[t * 16 + col];
      bbv[t] = bbp[t * 16 + col];
    }
#pragma unroll
    for (int r = 0; r < 4; r++) {
      float s1 = c2[0][r] + c2[1][r] + c2[2][r] + c2[3][r];
      float s2 = c2[0][r] * c2[0][r] + c2[1][r] * c2[1][r] +
                 c2[2][r] * c2[2][r] + c2[3][r] * c2[3][r];
#pragma unroll
      for (int o = 1; o < 16; o <<= 1) {
        s1 += __shfl_xor(s1, o);
        s2 += __shfl_xor(s2, o);
      }
      float mu = s1 * (1.0f / 64.0f);
      float var = s2 * (1.0f / 64.0f) - mu * mu;
      float rr = rsqrtf(var + 1e-5f);
#pragma unroll
      for (int t = 0; t < 4; t++)
        hacc[r][t] += (c2[t][r] - mu) * rr * gav[t] + bbv[t];
    }
  }

#pragma unroll
  for (int r = 0; r < 4; r++) {
    int gm = m0 + wv * 16 + quad * 4 + r;
    if (gm < NN) {
#pragma unroll
      for (int t = 0; t < 4; t++)
        A.hout[(size_t)gm * 64 + t * 16 + col] = hacc[r][t];
    }
  }
}

// ---------------- decoder ----------------
__global__ __launch_bounds__(256) void k_out(const float* __restrict__ pooled,
                                             const float* __restrict__ W,
                                             const float* __restrict__ b,
                                             float* __restrict__ out) {
  int gid = blockIdx.x * 256 + threadIdx.x;
  if (gid >= SS * DD) return;
  int s = gid >> 6, d = gid & 63;
  const float* pr = pooled + (size_t)s * DD;
  float acc = b[d];
#pragma unroll
  for (int k = 0; k < DD; k++) acc += pr[k] * W[k * DD + d];
  out[gid] = acc;
}

extern "C" void kernel_launch(void* const* d_in, const int* in_sizes, int n_in,
                              void* d_out, int out_size, void* d_ws, size_t ws_size,
                              hipStream_t stream) {
  const float* x = (const float*)d_in[0];
  const float* edge_attr = (const float*)d_in[1];
  const int* edge_index = (const int*)d_in[2];
  const int* node_idx = (const int*)d_in[3];
  const int* root_idx = (const int*)d_in[4];
  const int* transpose_idx = (const int*)d_in[5];
  const float* W_init = (const float*)d_in[6];
  const float* b_init = (const float*)d_in[7];
  const float* lu_We = (const float*)d_in[8];
  const float* lu_be = (const float*)d_in[9];
  const float* eps_[4] = {(const float*)d_in[10], (const float*)d_in[17],
                          (const float*)d_in[24], (const float*)d_in[31]};
  const float* W1_[4] = {(const float*)d_in[11], (const float*)d_in[18],
                         (const float*)d_in[25], (const float*)d_in[32]};
  const float* b1_[4] = {(const float*)d_in[12], (const float*)d_in[19],
                         (const float*)d_in[26], (const float*)d_in[33]};
  const float* W2_[4] = {(const float*)d_in[13], (const float*)d_in[20],
                         (const float*)d_in[27], (const float*)d_in[34]};
  const float* b2_[4] = {(const float*)d_in[14], (const float*)d_in[21],
                         (const float*)d_in[28], (const float*)d_in[35]};
  const float* ga_[4] = {(const float*)d_in[15], (const float*)d_in[22],
                         (const float*)d_in[29], (const float*)d_in[36]};
  const float* bn_[4] = {(const float*)d_in[16], (const float*)d_in[23],
                         (const float*)d_in[30], (const float*)d_in[37]};
  const float* W_jk = (const float*)d_in[38];
  const float* b_jk = (const float*)d_in[39];

  // ---- workspace carve ----
  char* p = (char*)d_ws;
  auto carve = [&](size_t bytes) -> char* {
    char* r = p;
    p += (bytes + 255) & ~(size_t)255;
    return r;
  };
  float* h0 = (float*)carve((size_t)NN * DD * 4);
  float* h1 = (float*)carve((size_t)NN * DD * 4);
  float* agg = (float*)carve((size_t)NN * DD * 4);
  float* gsum = (float*)carve(SS * DD * 4);
  float* cnt = (float*)carve(SS * 4);
  float* pooled = (float*)carve(SS * DD * 4);
  short* wbt = (short*)carve(24 * 4096 * 2);
  int* ecnt = (int*)carve(NN * 4);
  int* eoff = (int*)carve(NN * 4);
  int* ecurs = (int*)carve(NN * 4);
  int* ebsum = (int*)carve(256 * 4);
  int2* epk = (int2*)carve((size_t)EE * 8);
  int* ncnt = (int*)carve(SS * 4);
  int* noff = (int*)carve(SS * 4);
  int* ncurs = (int*)carve(SS * 4);
  int* nbsum = (int*)carve(256 * 4);
  int* nsorted = (int*)carve(NN * 4);

  const int* srcp = edge_index;
  const int* dstp = edge_index + EE;

  // ---- build CSRs (identical work every call; graph-capture safe) ----
  hipMemsetAsync(ecnt, 0, NN * 4, stream);
  hipMemsetAsync(ncnt, 0, SS * 4, stream);
  k_hist<<<(EE + 255) / 256, 256, 0, stream>>>(dstp, ecnt, EE);
  k_hist<<<(NN + 255) / 256, 256, 0, stream>>>(node_idx, ncnt, NN);
  k_scan1<<<SNB, 256, 0, stream>>>(ecnt, eoff, ecurs, ebsum, NN);
  k_scan2<<<1, 256, 0, stream>>>(ebsum, SNB);
  k_scan3<<<SNB, 256, 0, stream>>>(eoff, ecurs, ebsum, NN);
  k_scan1<<<1, 256, 0, stream>>>(ncnt, noff, ncurs, nbsum, SS);  // SS<=1024: one block
  k_bucket_e<<<(EE + 255) / 256, 256, 0, stream>>>(srcp, dstp, ecurs, epk);
  k_bucket_n<<<(NN + 255) / 256, 256, 0, stream>>>(node_idx, ncurs, nsorted);
  k_cntf<<<(SS + 255) / 256, 256, 0, stream>>>(ncnt, cnt);

  k_init<<<(NN * DD) / 256, 256, 0, stream>>>(x, W_init, b_init, h0);

  WPrep P;
  for (int b = 0; b < 4; b++) {
    P.W[b * 2 + 0] = W1_[b];
    P.W[b * 2 + 1] = W2_[b];
  }
  k_wprep<<<(24 * 4096) / 256, 256, 0, stream>>>(P, wbt);

  float* hc = h0;
  float* hn = h1;
  for (int l = 0; l < NL; l++) {
    k_edge2<<<(NN + 3) / 4, 256, 0, stream>>>(hc, edge_attr, epk, eoff, ecnt,
                                              lu_We + (size_t)l * FEE * DD,
                                              lu_be + l * DD, agg);
    k_seg<<<SS, 256, 0, stream>>>(hc, nsorted, noff, ncnt, gsum);

    NodeArgs A;
    A.h = hc; A.agg = agg; A.gsum = gsum; A.cnt = cnt;
    A.nidx = node_idx; A.root = root_idx; A.tr = transpose_idx;
    for (int b = 0; b < 4; b++) {
      A.eps[b] = eps_[b] + l;
      A.wt1[b] = wbt + ((size_t)(b * 2 + 0) * NL + l) * 4096;
      A.wt2[b] = wbt + ((size_t)(b * 2 + 1) * NL + l) * 4096;
      A.b1[b] = b1_[b] + l * DD;
      A.b2[b] = b2_[b] + l * DD;
      A.ga[b] = ga_[b] + l * DD;
      A.bb[b] = bn_[b] + l * DD;
    }
    A.hout = hn;
    k_node<<<(NN + 63) / 64, 256, 0, stream>>>(A);
    float* tmp = hc; hc = hn; hn = tmp;
  }

  k_seg<<<SS, 256, 0, stream>>>(hc, nsorted, noff, ncnt, pooled);
  k_out<<<(SS * DD + 255) / 256, 256, 0, stream>>>(pooled, W_jk, b_jk, (float*)d_out);
}

// Round 5
// 1420.283 us; speedup vs baseline: 1.8521x; 1.0818x over previous
//
#include <hip/hip_runtime.h>

#define NN 250000
#define EE 1000000
#define SS 1000
#define DD 64
#define FIN 16
#define FEE 8
#define NL 3
#define LDH 72  // LDS row stride in bf16 elems (144 B/row: 16B-aligned, 2-way bank alias max)
#define SCHUNK 1024
#define SNB ((NN + SCHUNK - 1) / SCHUNK)  // 245

typedef __attribute__((ext_vector_type(8))) short bf16x8;
typedef __attribute__((ext_vector_type(4))) float f32x4;

static __device__ __forceinline__ short f2bf(float f) {
  union { float f; unsigned u; } v{f};
  unsigned r = (v.u + 0x7fffu + ((v.u >> 16) & 1u)) >> 16;  // RNE
  return (short)r;
}
static __device__ __forceinline__ float bfl(unsigned u) {
  union { unsigned u; float f; } v{u << 16};
  return v.f;
}
static __device__ __forceinline__ float bfh(unsigned u) {
  union { unsigned u; float f; } v{u & 0xffff0000u};
  return v.f;
}
static __device__ __forceinline__ float bfu(unsigned short u) {
  union { unsigned u; float f; } v{(unsigned)u << 16};
  return v.f;
}
static __device__ __forceinline__ unsigned pack2(float a, float b) {
  return (unsigned)(unsigned short)f2bf(a) | ((unsigned)(unsigned short)f2bf(b) << 16);
}

// ---------------- histogram ----------------
__global__ __launch_bounds__(256) void k_hist(const int* __restrict__ idx,
                                              int* __restrict__ cnt, int n) {
  int i = blockIdx.x * 256 + threadIdx.x;
  if (i < n) atomicAdd(&cnt[idx[i]], 1);
}

// ---------------- block-local exclusive scan (chunk=1024) ----------------
__global__ __launch_bounds__(256) void k_scan1(const int* __restrict__ cntv,
                                               int* __restrict__ off,
                                               int* __restrict__ curs,
                                               int* __restrict__ bsums, int n) {
  __shared__ int ls[256];
  int b = blockIdx.x, t = threadIdx.x;
  int base = b * SCHUNK + t * 4;
  int v[4];
#pragma unroll
  for (int j = 0; j < 4; j++) v[j] = (base + j < n) ? cntv[base + j] : 0;
  int s4 = v[0] + v[1] + v[2] + v[3];
  ls[t] = s4;
  __syncthreads();
  for (int o = 1; o < 256; o <<= 1) {
    int x = (t >= o) ? ls[t - o] : 0;
    __syncthreads();
    ls[t] += x;
    __syncthreads();
  }
  int run = ls[t] - s4;
#pragma unroll
  for (int j = 0; j < 4; j++) {
    if (base + j < n) { off[base + j] = run; curs[base + j] = run; }
    run += v[j];
  }
  if (t == 255) bsums[b] = ls[255];
}

__global__ __launch_bounds__(256) void k_scan2(int* __restrict__ bsums, int nb) {
  __shared__ int ls[256];
  int t = threadIdx.x;
  int v = (t < nb) ? bsums[t] : 0;
  ls[t] = v;
  __syncthreads();
  for (int o = 1; o < 256; o <<= 1) {
    int x = (t >= o) ? ls[t - o] : 0;
    __syncthreads();
    ls[t] += x;
    __syncthreads();
  }
  if (t < nb) bsums[t] = ls[t] - v;  // exclusive
}

__global__ __launch_bounds__(256) void k_scan3(int* __restrict__ off,
                                               int* __restrict__ curs,
                                               const int* __restrict__ bsums, int n) {
  int b = blockIdx.x, t = threadIdx.x;
  int add = bsums[b];
  int base = b * SCHUNK + t * 4;
#pragma unroll
  for (int j = 0; j < 4; j++)
    if (base + j < n) { off[base + j] += add; curs[base + j] += add; }
}

// ---------------- bucket scatter: src + bf16 edge-attrs in CSR order ----------------
__global__ __launch_bounds__(256) void k_bucket_e(const int* __restrict__ src,
                                                  const int* __restrict__ dst,
                                                  const float* __restrict__ ea,
                                                  int* __restrict__ curs,
                                                  int* __restrict__ ssrc,
                                                  unsigned short* __restrict__ eas) {
  int e = blockIdx.x * 256 + threadIdx.x;
  if (e >= EE) return;
  int pos = atomicAdd(&curs[dst[e]], 1);
  ssrc[pos] = src[e];
  const float* a = &ea[(size_t)e * 8];
  uint4 p;
  p.x = pack2(a[0], a[1]);
  p.y = pack2(a[2], a[3]);
  p.z = pack2(a[4], a[5]);
  p.w = pack2(a[6], a[7]);
  *(uint4*)&eas[(size_t)pos * 8] = p;
}

__global__ __launch_bounds__(256) void k_bucket_n(const int* __restrict__ nidx,
                                                  int* __restrict__ curs,
                                                  int* __restrict__ nsorted) {
  int n = blockIdx.x * 256 + threadIdx.x;
  if (n >= NN) return;
  int pos = atomicAdd(&curs[nidx[n]], 1);
  nsorted[pos] = n;
}

__global__ __launch_bounds__(256) void k_cntf(const int* __restrict__ ncnt,
                                              float* __restrict__ cnt) {
  int s = blockIdx.x * 256 + threadIdx.x;
  if (s < SS) {
    float c = (float)ncnt[s];
    cnt[s] = c < 1.0f ? 1.0f : c;
  }
}

// ---------------- init encoder: hb = bf16(x @ W_init + b) ----------------
__global__ __launch_bounds__(256) void k_init(const float* __restrict__ x,
                                              const float* __restrict__ W,
                                              const float* __restrict__ b,
                                              unsigned short* __restrict__ hb) {
  int gid = blockIdx.x * 256 + threadIdx.x;
  int n = gid >> 6, d = gid & 63;
  const float* xr = x + (size_t)n * FIN;
  float acc = b[d];
#pragma unroll
  for (int k = 0; k < FIN; k++) acc += xr[k] * W[k * DD + d];
  hb[gid] = (unsigned short)f2bf(acc);
}

// ---------------- weight prep: bf16 W^T ----------------
struct WPrep { const float* W[8]; };

__global__ __launch_bounds__(256) void k_wprep(WPrep P, short* __restrict__ wbt) {
  int gid = blockIdx.x * 256 + threadIdx.x;  // 24*4096
  int slot = gid >> 12;
  int e = gid & 4095;
  int n = e >> 6, k = e & 63;
  int bg = slot / NL, l = slot % NL;
  float v = P.W[bg][(size_t)l * 4096 + k * 64 + n];
  wbt[gid] = f2bf(v);
}

// ---------------- CSR edge aggregation (bf16 gather, unroll-4), bf16 agg out ----------------
__global__ __launch_bounds__(256) void k_edge2(const unsigned short* __restrict__ hb,
                                               const unsigned short* __restrict__ eas,
                                               const int* __restrict__ ssrc,
                                               const int* __restrict__ eoff,
                                               const int* __restrict__ ecnt,
                                               const float* __restrict__ We,
                                               const float* __restrict__ be,
                                               unsigned short* __restrict__ aggb) {
  int v = blockIdx.x * 4 + (threadIdx.x >> 6);
  int d = threadIdx.x & 63;
  if (v >= NN) return;
  float w[8];
#pragma unroll
  for (int k = 0; k < 8; k++) w[k] = We[k * 64 + d];
  float bed = be[d];
  int base = eoff[v], deg = ecnt[v];
  float acc = 0.0f;
  int i = 0;
  for (; i + 4 <= deg; i += 4) {
    int s0 = ssrc[base + i + 0];
    int s1 = ssrc[base + i + 1];
    int s2 = ssrc[base + i + 2];
    int s3 = ssrc[base + i + 3];
    unsigned short g0 = hb[(size_t)s0 * 64 + d];
    unsigned short g1 = hb[(size_t)s1 * 64 + d];
    unsigned short g2 = hb[(size_t)s2 * 64 + d];
    unsigned short g3 = hb[(size_t)s3 * 64 + d];
    uint4 a0 = *(const uint4*)&eas[(size_t)(base + i + 0) * 8];
    uint4 a1 = *(const uint4*)&eas[(size_t)(base + i + 1) * 8];
    uint4 a2 = *(const uint4*)&eas[(size_t)(base + i + 2) * 8];
    uint4 a3 = *(const uint4*)&eas[(size_t)(base + i + 3) * 8];
    float e0 = bed + bfl(a0.x) * w[0] + bfh(a0.x) * w[1] + bfl(a0.y) * w[2] + bfh(a0.y) * w[3] +
               bfl(a0.z) * w[4] + bfh(a0.z) * w[5] + bfl(a0.w) * w[6] + bfh(a0.w) * w[7];
    float e1 = bed + bfl(a1.x) * w[0] + bfh(a1.x) * w[1] + bfl(a1.y) * w[2] + bfh(a1.y) * w[3] +
               bfl(a1.z) * w[4] + bfh(a1.z) * w[5] + bfl(a1.w) * w[6] + bfh(a1.w) * w[7];
    float e2 = bed + bfl(a2.x) * w[0] + bfh(a2.x) * w[1] + bfl(a2.y) * w[2] + bfh(a2.y) * w[3] +
               bfl(a2.z) * w[4] + bfh(a2.z) * w[5] + bfl(a2.w) * w[6] + bfh(a2.w) * w[7];
    float e3 = bed + bfl(a3.x) * w[0] + bfh(a3.x) * w[1] + bfl(a3.y) * w[2] + bfh(a3.y) * w[3] +
               bfl(a3.z) * w[4] + bfh(a3.z) * w[5] + bfl(a3.w) * w[6] + bfh(a3.w) * w[7];
    float m0 = bfu(g0) + e0;
    float m1 = bfu(g1) + e1;
    float m2 = bfu(g2) + e2;
    float m3 = bfu(g3) + e3;
    acc += (m0 > 0.0f ? m0 : 0.0f) + (m1 > 0.0f ? m1 : 0.0f) +
           (m2 > 0.0f ? m2 : 0.0f) + (m3 > 0.0f ? m3 : 0.0f);
  }
  for (; i < deg; i++) {
    int s0 = ssrc[base + i];
    unsigned short g0 = hb[(size_t)s0 * 64 + d];
    uint4 a0 = *(const uint4*)&eas[(size_t)(base + i) * 8];
    float e0 = bed + bfl(a0.x) * w[0] + bfh(a0.x) * w[1] + bfl(a0.y) * w[2] + bfh(a0.y) * w[3] +
               bfl(a0.z) * w[4] + bfh(a0.z) * w[5] + bfl(a0.w) * w[6] + bfh(a0.w) * w[7];
    float m0 = bfu(g0) + e0;
    acc += m0 > 0.0f ? m0 : 0.0f;
  }
  aggb[(size_t)v * 64 + d] = (unsigned short)f2bf(acc);
}

// ---------------- CSR segment sum over bf16 h -> fp32 out ----------------
__global__ __launch_bounds__(256) void k_seg(const unsigned short* __restrict__ hb,
                                             const int* __restrict__ nsorted,
                                             const int* __restrict__ noff,
                                             const int* __restrict__ ncnt,
                                             float* __restrict__ out) {
  __shared__ float red[256];
  int s = blockIdx.x;
  int t = threadIdx.x;
  int ch = t & 63, r = t >> 6;
  int base = noff[s], c = ncnt[s];
  float acc = 0.0f;
  for (int i = r; i < c; i += 4) {
    int n = nsorted[base + i];
    acc += bfu(hb[(size_t)n * 64 + ch]);
  }
  red[t] = acc;
  __syncthreads();
  if (r == 0)
    out[s * 64 + ch] = red[ch] + red[64 + ch] + red[128 + ch] + red[192 + ch];
}

// ---------------- fused node kernel (MFMA) ----------------
struct NodeArgs {
  const unsigned short* hb;
  const unsigned short* aggb;
  const float* gsum;
  const float* cnt;
  const int* nidx;
  const int* root;
  const int* tr;
  const float* eps[4];
  const short* wt1[4];
  const short* wt2[4];
  const float* b1[4];
  const float* b2[4];
  const float* ga[4];
  const float* bb[4];
  unsigned short* hbout;
};

__global__ __launch_bounds__(256) void k_node(NodeArgs A) {
  __shared__ short sU[64 * LDH];
  __shared__ short sT[64 * LDH];
  __shared__ int sSeg[64];
  __shared__ int sRowV[64];
  __shared__ int sRowT[64];
  __shared__ float sInv[64];

  int tid = threadIdx.x;
  int m0 = blockIdx.x * 64;
  int wv = tid >> 6;
  int lane = tid & 63;
  int col = lane & 15;
  int quad = lane >> 4;

  if (tid < 64) {
    int gm = m0 + tid;
    if (gm >= NN) gm = 0;
    int s = A.nidx[gm];
    sSeg[tid] = s;
    sRowV[tid] = A.root[s];
    sRowT[tid] = A.tr[gm];
    float c = A.cnt[s];
    if (c < 1.0f) c = 1.0f;
    sInv[tid] = 1.0f / c;
  }

  float hacc[4][4];
#pragma unroll
  for (int i = 0; i < 4; i++)
#pragma unroll
    for (int j = 0; j < 4; j++) hacc[i][j] = 0.0f;

  int arow = wv * 16 + col;

  for (int b = 0; b < 4; b++) {
    float aeps = 1.0f + A.eps[b][0];
    __syncthreads();

    // Phase A: sU[m][k] = bf16(aeps*h[m][k] + other[m][k]); 8 elems/thread/iter
    for (int idx = tid; idx < 64 * 8; idx += 256) {
      int m = idx >> 3, c8 = (idx & 7) * 8;
      int gm = m0 + m;
      if (gm >= NN) gm = 0;
      uint4 hq = *(const uint4*)&A.hb[(size_t)gm * 64 + c8];
      float hv[8] = {bfl(hq.x), bfh(hq.x), bfl(hq.y), bfh(hq.y),
                     bfl(hq.z), bfh(hq.z), bfl(hq.w), bfh(hq.w)};
      float ov[8];
      if (b == 0) {
        uint4 q = *(const uint4*)&A.aggb[(size_t)gm * 64 + c8];
        ov[0] = bfl(q.x); ov[1] = bfh(q.x); ov[2] = bfl(q.y); ov[3] = bfh(q.y);
        ov[4] = bfl(q.z); ov[5] = bfh(q.z); ov[6] = bfl(q.w); ov[7] = bfh(q.w);
      } else if (b == 1 || b == 2) {
        int r = (b == 1) ? sRowV[m] : sRowT[m];
        uint4 q = *(const uint4*)&A.hb[(size_t)r * 64 + c8];
        ov[0] = bfl(q.x); ov[1] = bfh(q.x); ov[2] = bfl(q.y); ov[3] = bfh(q.y);
        ov[4] = bfl(q.z); ov[5] = bfh(q.z); ov[6] = bfl(q.w); ov[7] = bfh(q.w);
      } else {
        int s = sSeg[m];
        float iv = sInv[m];
        float4 g0 = *(const float4*)&A.gsum[s * 64 + c8];
        float4 g1 = *(const float4*)&A.gsum[s * 64 + c8 + 4];
        ov[0] = g0.x * iv; ov[1] = g0.y * iv; ov[2] = g0.z * iv; ov[3] = g0.w * iv;
        ov[4] = g1.x * iv; ov[5] = g1.y * iv; ov[6] = g1.z * iv; ov[7] = g1.w * iv;
      }
      uint4 o;
      o.x = pack2(aeps * hv[0] + ov[0], aeps * hv[1] + ov[1]);
      o.y = pack2(aeps * hv[2] + ov[2], aeps * hv[3] + ov[3]);
      o.z = pack2(aeps * hv[4] + ov[4], aeps * hv[5] + ov[5]);
      o.w = pack2(aeps * hv[6] + ov[6], aeps * hv[7] + ov[7]);
      *(uint4*)&sU[m * LDH + c8] = o;
    }
    __syncthreads();

    const short* w1 = A.wt1[b];
    const short* w2 = A.wt2[b];
    const float* b1p = A.b1[b];
    const float* b2p = A.b2[b];

    bf16x8 a0 = *(const bf16x8*)&sU[arow * LDH + quad * 8];
    bf16x8 a1 = *(const bf16x8*)&sU[arow * LDH + 32 + quad * 8];

#pragma unroll
    for (int t = 0; t < 4; t++) {
      int n = t * 16 + col;
      bf16x8 w0 = *(const bf16x8*)&w1[n * 64 + quad * 8];
      bf16x8 wk = *(const bf16x8*)&w1[n * 64 + 32 + quad * 8];
      float bv = b1p[n];
      f32x4 c = {bv, bv, bv, bv};
      c = __builtin_amdgcn_mfma_f32_16x16x32_bf16(a0, w0, c, 0, 0, 0);
      c = __builtin_amdgcn_mfma_f32_16x16x32_bf16(a1, wk, c, 0, 0, 0);
#pragma unroll
      for (int r = 0; r < 4; r++) {
        float v = c[r];
        v = v > 0.0f ? v : 0.0f;
        sT[(wv * 16 + quad * 4 + r) * LDH + n] = f2bf(v);
      }
    }

    bf16x8 t0 = *(const bf16x8*)&sT[arow * LDH + quad * 8];
    bf16x8 t1 = *(const bf16x8*)&sT[arow * LDH + 32 + quad * 8];

    f32x4 c2[4];
#pragma unroll
    for (int t = 0; t < 4; t++) {
      int n = t * 16 + col;
      bf16x8 w0 = *(const bf16x8*)&w2[n * 64 + quad * 8];
      bf16x8 wk = *(const bf16x8*)&w2[n * 64 + 32 + quad * 8];
      float bv = b2p[n];
      f32x4 c = {bv, bv, bv, bv};
      c = __builtin_amdgcn_mfma_f32_16x16x32_bf16(t0, w0, c, 0, 0, 0);
      c = __builtin_amdgcn_mfma_f32_16x16x32_bf16(t1, wk, c, 0, 0, 0);
      c2[t] = c;
    }

    const float* ga = A.ga[b];
    const float* bbp = A.bb[b];
    float gav[4], bbv[4];
#pragma unroll
    for (int t = 0; t < 4; t++) {
      gav[t] = ga[t * 16 + col];
      bbv[t] = bbp[t * 16 + col];
    }
#pragma unroll
    for (int r = 0; r < 4; r++) {
      float s1 = c2[0][r] + c2[1][r] + c2[2][r] + c2[3][r];
      float s2 = c2[0][r] * c2[0][r] + c2[1][r] * c2[1][r] +
                 c2[2][r] * c2[2][r] + c2[3][r] * c2[3][r];
#pragma unroll
      for (int o = 1; o < 16; o <<= 1) {
        s1 += __shfl_xor(s1, o);
        s2 += __shfl_xor(s2, o);
      }
      float mu = s1 * (1.0f / 64.0f);
      float var = s2 * (1.0f / 64.0f) - mu * mu;
      float rr = rsqrtf(var + 1e-5f);
#pragma unroll
      for (int t = 0; t < 4; t++)
        hacc[r][t] += (c2[t][r] - mu) * rr * gav[t] + bbv[t];
    }
  }

#pragma unroll
  for (int r = 0; r < 4; r++) {
    int gm = m0 + wv * 16 + quad * 4 + r;
    if (gm < NN) {
#pragma unroll
      for (int t = 0; t < 4; t++)
        A.hbout[(size_t)gm * 64 + t * 16 + col] = (unsigned short)f2bf(hacc[r][t]);
    }
  }
}

// ---------------- decoder ----------------
__global__ __launch_bounds__(256) void k_out(const float* __restrict__ pooled,
                                             const float* __restrict__ W,
                                             const float* __restrict__ b,
                                             float* __restrict__ out) {
  int gid = blockIdx.x * 256 + threadIdx.x;
  if (gid >= SS * DD) return;
  int s = gid >> 6, d = gid & 63;
  const float* pr = pooled + (size_t)s * DD;
  float acc = b[d];
#pragma unroll
  for (int k = 0; k < DD; k++) acc += pr[k] * W[k * DD + d];
  out[gid] = acc;
}

extern "C" void kernel_launch(void* const* d_in, const int* in_sizes, int n_in,
                              void* d_out, int out_size, void* d_ws, size_t ws_size,
                              hipStream_t stream) {
  const float* x = (const float*)d_in[0];
  const float* edge_attr = (const float*)d_in[1];
  const int* edge_index = (const int*)d_in[2];
  const int* node_idx = (const int*)d_in[3];
  const int* root_idx = (const int*)d_in[4];
  const int* transpose_idx = (const int*)d_in[5];
  const float* W_init = (const float*)d_in[6];
  const float* b_init = (const float*)d_in[7];
  const float* lu_We = (const float*)d_in[8];
  const float* lu_be = (const float*)d_in[9];
  const float* eps_[4] = {(const float*)d_in[10], (const float*)d_in[17],
                          (const float*)d_in[24], (const float*)d_in[31]};
  const float* W1_[4] = {(const float*)d_in[11], (const float*)d_in[18],
                         (const float*)d_in[25], (const float*)d_in[32]};
  const float* b1_[4] = {(const float*)d_in[12], (const float*)d_in[19],
                         (const float*)d_in[26], (const float*)d_in[33]};
  const float* W2_[4] = {(const float*)d_in[13], (const float*)d_in[20],
                         (const float*)d_in[27], (const float*)d_in[34]};
  const float* b2_[4] = {(const float*)d_in[14], (const float*)d_in[21],
                         (const float*)d_in[28], (const float*)d_in[35]};
  const float* ga_[4] = {(const float*)d_in[15], (const float*)d_in[22],
                         (const float*)d_in[29], (const float*)d_in[36]};
  const float* bn_[4] = {(const float*)d_in[16], (const float*)d_in[23],
                         (const float*)d_in[30], (const float*)d_in[37]};
  const float* W_jk = (const float*)d_in[38];
  const float* b_jk = (const float*)d_in[39];

  // ---- workspace carve (~122 MB total; R3's working set was ~205 MB) ----
  char* p = (char*)d_ws;
  auto carve = [&](size_t bytes) -> char* {
    char* r = p;
    p += (bytes + 255) & ~(size_t)255;
    return r;
  };
  unsigned short* hb0 = (unsigned short*)carve((size_t)NN * DD * 2);   // 32 MB
  unsigned short* hb1 = (unsigned short*)carve((size_t)NN * DD * 2);   // 32 MB
  unsigned short* aggb = (unsigned short*)carve((size_t)NN * DD * 2);  // 32 MB
  float* gsum = (float*)carve(SS * DD * 4);
  float* cnt = (float*)carve(SS * 4);
  float* pooled = (float*)carve(SS * DD * 4);
  short* wbt = (short*)carve(24 * 4096 * 2);
  int* ecnt = (int*)carve(NN * 4);
  int* eoff = (int*)carve(NN * 4);
  int* ecurs = (int*)carve(NN * 4);
  int* ebsum = (int*)carve(256 * 4);
  int* ssrc = (int*)carve((size_t)EE * 4);                             // 4 MB
  unsigned short* eas = (unsigned short*)carve((size_t)EE * FEE * 2);  // 16 MB
  int* ncnt = (int*)carve(SS * 4);
  int* noff = (int*)carve(SS * 4);
  int* ncurs = (int*)carve(SS * 4);
  int* nbsum = (int*)carve(256 * 4);
  int* nsorted = (int*)carve(NN * 4);

  const int* srcp = edge_index;
  const int* dstp = edge_index + EE;

  // ---- build CSRs (identical work every call; graph-capture safe) ----
  hipMemsetAsync(ecnt, 0, NN * 4, stream);
  hipMemsetAsync(ncnt, 0, SS * 4, stream);
  k_hist<<<(EE + 255) / 256, 256, 0, stream>>>(dstp, ecnt, EE);
  k_hist<<<(NN + 255) / 256, 256, 0, stream>>>(node_idx, ncnt, NN);
  k_scan1<<<SNB, 256, 0, stream>>>(ecnt, eoff, ecurs, ebsum, NN);
  k_scan2<<<1, 256, 0, stream>>>(ebsum, SNB);
  k_scan3<<<SNB, 256, 0, stream>>>(eoff, ecurs, ebsum, NN);
  k_scan1<<<1, 256, 0, stream>>>(ncnt, noff, ncurs, nbsum, SS);
  k_bucket_e<<<(EE + 255) / 256, 256, 0, stream>>>(srcp, dstp, edge_attr, ecurs, ssrc, eas);
  k_bucket_n<<<(NN + 255) / 256, 256, 0, stream>>>(node_idx, ncurs, nsorted);
  k_cntf<<<(SS + 255) / 256, 256, 0, stream>>>(ncnt, cnt);

  k_init<<<(NN * DD) / 256, 256, 0, stream>>>(x, W_init, b_init, hb0);

  WPrep P;
  for (int b = 0; b < 4; b++) {
    P.W[b * 2 + 0] = W1_[b];
    P.W[b * 2 + 1] = W2_[b];
  }
  k_wprep<<<(24 * 4096) / 256, 256, 0, stream>>>(P, wbt);

  unsigned short* hbc = hb0;
  unsigned short* hbn = hb1;
  for (int l = 0; l < NL; l++) {
    k_edge2<<<(NN + 3) / 4, 256, 0, stream>>>(hbc, eas, ssrc, eoff, ecnt,
                                              lu_We + (size_t)l * FEE * DD,
                                              lu_be + l * DD, aggb);
    k_seg<<<SS, 256, 0, stream>>>(hbc, nsorted, noff, ncnt, gsum);

    NodeArgs A;
    A.hb = hbc; A.aggb = aggb; A.gsum = gsum; A.cnt = cnt;
    A.nidx = node_idx; A.root = root_idx; A.tr = transpose_idx;
    for (int b = 0; b < 4; b++) {
      A.eps[b] = eps_[b] + l;
      A.wt1[b] = wbt + ((size_t)(b * 2 + 0) * NL + l) * 4096;
      A.wt2[b] = wbt + ((size_t)(b * 2 + 1) * NL + l) * 4096;
      A.b1[b] = b1_[b] + l * DD;
      A.b2[b] = b2_[b] + l * DD;
      A.ga[b] = ga_[b] + l * DD;
      A.bb[b] = bn_[b] + l * DD;
    }
    A.hbout = hbn;
    k_node<<<(NN + 63) / 64, 256, 0, stream>>>(A);
    unsigned short* tmpb = hbc; hbc = hbn; hbn = tmpb;
  }

  k_seg<<<SS, 256, 0, stream>>>(hbc, nsorted, noff, ncnt, pooled);
  k_out<<<(SS * DD + 255) / 256, 256, 0, stream>>>(pooled, W_jk, b_jk, (float*)d_out);
}

// Round 6
// 1316.389 us; speedup vs baseline: 1.9983x; 1.0789x over previous
//
#include <hip/hip_runtime.h>

#define NN 250000
#define EE 1000000
#define SS 1000
#define DD 64
#define FIN 16
#define FEE 8
#define NL 3
#define LDH 72  // sT band row stride (bf16 elems); 144B row -> 2-way bank alias (free)
#define SCHUNK 1024
#define SNB ((NN + SCHUNK - 1) / SCHUNK)  // 245
#define EB (NN / 4)                        // 62500 edge blocks in producer

typedef __attribute__((ext_vector_type(8))) short bf16x8;
typedef __attribute__((ext_vector_type(4))) float f32x4;

static __device__ __forceinline__ short f2bf(float f) {
  union { float f; unsigned u; } v{f};
  unsigned r = (v.u + 0x7fffu + ((v.u >> 16) & 1u)) >> 16;  // RNE
  return (short)r;
}
static __device__ __forceinline__ float bfl(unsigned u) {
  union { unsigned u; float f; } v{u << 16};
  return v.f;
}
static __device__ __forceinline__ float bfh(unsigned u) {
  union { unsigned u; float f; } v{u & 0xffff0000u};
  return v.f;
}
static __device__ __forceinline__ float bfu(unsigned short u) {
  union { unsigned u; float f; } v{(unsigned)u << 16};
  return v.f;
}
static __device__ __forceinline__ unsigned pack2(float a, float b) {
  return (unsigned)(unsigned short)f2bf(a) | ((unsigned)(unsigned short)f2bf(b) << 16);
}
static __device__ __forceinline__ void unp8(uint4 v, float* o) {
  o[0] = bfl(v.x); o[1] = bfh(v.x); o[2] = bfl(v.y); o[3] = bfh(v.y);
  o[4] = bfl(v.z); o[5] = bfh(v.z); o[6] = bfl(v.w); o[7] = bfh(v.w);
}

// ---------------- histogram ----------------
__global__ __launch_bounds__(256) void k_hist(const int* __restrict__ idx,
                                              int* __restrict__ cnt, int n) {
  int i = blockIdx.x * 256 + threadIdx.x;
  if (i < n) atomicAdd(&cnt[idx[i]], 1);
}

// ---------------- block-local exclusive scan (chunk=1024) ----------------
__global__ __launch_bounds__(256) void k_scan1(const int* __restrict__ cntv,
                                               int* __restrict__ off,
                                               int* __restrict__ curs,
                                               int* __restrict__ bsums, int n) {
  __shared__ int ls[256];
  int b = blockIdx.x, t = threadIdx.x;
  int base = b * SCHUNK + t * 4;
  int v[4];
#pragma unroll
  for (int j = 0; j < 4; j++) v[j] = (base + j < n) ? cntv[base + j] : 0;
  int s4 = v[0] + v[1] + v[2] + v[3];
  ls[t] = s4;
  __syncthreads();
  for (int o = 1; o < 256; o <<= 1) {
    int x = (t >= o) ? ls[t - o] : 0;
    __syncthreads();
    ls[t] += x;
    __syncthreads();
  }
  int run = ls[t] - s4;
#pragma unroll
  for (int j = 0; j < 4; j++) {
    if (base + j < n) { off[base + j] = run; curs[base + j] = run; }
    run += v[j];
  }
  if (t == 255) bsums[b] = ls[255];
}

__global__ __launch_bounds__(256) void k_scan2(int* __restrict__ bsums, int nb) {
  __shared__ int ls[256];
  int t = threadIdx.x;
  int v = (t < nb) ? bsums[t] : 0;
  ls[t] = v;
  __syncthreads();
  for (int o = 1; o < 256; o <<= 1) {
    int x = (t >= o) ? ls[t - o] : 0;
    __syncthreads();
    ls[t] += x;
    __syncthreads();
  }
  if (t < nb) bsums[t] = ls[t] - v;  // exclusive
}

__global__ __launch_bounds__(256) void k_scan3(int* __restrict__ off,
                                               int* __restrict__ curs,
                                               const int* __restrict__ bsums, int n) {
  int b = blockIdx.x, t = threadIdx.x;
  int add = bsums[b];
  int base = b * SCHUNK + t * 4;
#pragma unroll
  for (int j = 0; j < 4; j++)
    if (base + j < n) { off[base + j] += add; curs[base + j] += add; }
}

// ---------------- bucket scatter: src + bf16 edge-attrs in CSR order ----------------
__global__ __launch_bounds__(256) void k_bucket_e(const int* __restrict__ src,
                                                  const int* __restrict__ dst,
                                                  const float* __restrict__ ea,
                                                  int* __restrict__ curs,
                                                  int* __restrict__ ssrc,
                                                  unsigned short* __restrict__ eas) {
  int e = blockIdx.x * 256 + threadIdx.x;
  if (e >= EE) return;
  int pos = atomicAdd(&curs[dst[e]], 1);
  ssrc[pos] = src[e];
  const float* a = &ea[(size_t)e * 8];
  uint4 p;
  p.x = pack2(a[0], a[1]);
  p.y = pack2(a[2], a[3]);
  p.z = pack2(a[4], a[5]);
  p.w = pack2(a[6], a[7]);
  *(uint4*)&eas[(size_t)pos * 8] = p;
}

__global__ __launch_bounds__(256) void k_bucket_n(const int* __restrict__ nidx,
                                                  int* __restrict__ curs,
                                                  int* __restrict__ nsorted) {
  int n = blockIdx.x * 256 + threadIdx.x;
  if (n >= NN) return;
  int pos = atomicAdd(&curs[nidx[n]], 1);
  nsorted[pos] = n;
}

__global__ __launch_bounds__(256) void k_cinv(const int* __restrict__ ncnt,
                                              float* __restrict__ cinv) {
  int s = blockIdx.x * 256 + threadIdx.x;
  if (s < SS) {
    float c = (float)ncnt[s];
    cinv[s] = 1.0f / (c < 1.0f ? 1.0f : c);
  }
}

// ---------------- init encoder: hb = bf16(x @ W_init + b) ----------------
__global__ __launch_bounds__(256) void k_init(const float* __restrict__ x,
                                              const float* __restrict__ W,
                                              const float* __restrict__ b,
                                              unsigned short* __restrict__ hb) {
  int gid = blockIdx.x * 256 + threadIdx.x;
  int n = gid >> 6, d = gid & 63;
  const float* xr = x + (size_t)n * FIN;
  float acc = b[d];
#pragma unroll
  for (int k = 0; k < FIN; k++) acc += xr[k] * W[k * DD + d];
  hb[gid] = (unsigned short)f2bf(acc);
}

// ---------------- weight prep: bf16 W^T ----------------
struct WPrep { const float* W[8]; };

__global__ __launch_bounds__(256) void k_wprep(WPrep P, short* __restrict__ wbt) {
  int gid = blockIdx.x * 256 + threadIdx.x;  // 24*4096
  int slot = gid >> 12;
  int e = gid & 4095;
  int n = e >> 6, k = e & 63;
  int bg = slot / NL, l = slot % NL;
  float v = P.W[bg][(size_t)l * 4096 + k * 64 + n];
  wbt[gid] = f2bf(v);
}

// ---------------- fused producer: edge aggregation + segment mean (bf16) ----------------
struct ProdArgs {
  const unsigned short* hb;
  const unsigned short* eas;
  const int* ssrc;
  const int* eoff;
  const int* ecnt;
  const float* We;
  const float* be;
  unsigned short* aggb;
  const int* nsorted;
  const int* noff;
  const int* ncnt;
  const float* cinv;
  unsigned short* gsumb;
};

__global__ __launch_bounds__(256) void k_prod(ProdArgs P) {
  __shared__ float red[256];
  int tid = threadIdx.x;
  int blk = blockIdx.x;
  if (blk < EB) {
    // ---- edge path: agg[v] = sum relu(h[src]+ea@We+be), 4 nodes/block ----
    int v = blk * 4 + (tid >> 6);
    int d = tid & 63;
    float w[8];
#pragma unroll
    for (int k = 0; k < 8; k++) w[k] = P.We[k * 64 + d];
    float bed = P.be[d];
    int base = P.eoff[v], deg = P.ecnt[v];
    float acc = 0.0f;
    int i = 0;
    for (; i + 4 <= deg; i += 4) {
      int s0 = P.ssrc[base + i + 0];
      int s1 = P.ssrc[base + i + 1];
      int s2 = P.ssrc[base + i + 2];
      int s3 = P.ssrc[base + i + 3];
      unsigned short g0 = P.hb[(size_t)s0 * 64 + d];
      unsigned short g1 = P.hb[(size_t)s1 * 64 + d];
      unsigned short g2 = P.hb[(size_t)s2 * 64 + d];
      unsigned short g3 = P.hb[(size_t)s3 * 64 + d];
      uint4 a0 = *(const uint4*)&P.eas[(size_t)(base + i + 0) * 8];
      uint4 a1 = *(const uint4*)&P.eas[(size_t)(base + i + 1) * 8];
      uint4 a2 = *(const uint4*)&P.eas[(size_t)(base + i + 2) * 8];
      uint4 a3 = *(const uint4*)&P.eas[(size_t)(base + i + 3) * 8];
      float e0 = bed + bfl(a0.x) * w[0] + bfh(a0.x) * w[1] + bfl(a0.y) * w[2] + bfh(a0.y) * w[3] +
                 bfl(a0.z) * w[4] + bfh(a0.z) * w[5] + bfl(a0.w) * w[6] + bfh(a0.w) * w[7];
      float e1 = bed + bfl(a1.x) * w[0] + bfh(a1.x) * w[1] + bfl(a1.y) * w[2] + bfh(a1.y) * w[3] +
                 bfl(a1.z) * w[4] + bfh(a1.z) * w[5] + bfl(a1.w) * w[6] + bfh(a1.w) * w[7];
      float e2 = bed + bfl(a2.x) * w[0] + bfh(a2.x) * w[1] + bfl(a2.y) * w[2] + bfh(a2.y) * w[3] +
                 bfl(a2.z) * w[4] + bfh(a2.z) * w[5] + bfl(a2.w) * w[6] + bfh(a2.w) * w[7];
      float e3 = bed + bfl(a3.x) * w[0] + bfh(a3.x) * w[1] + bfl(a3.y) * w[2] + bfh(a3.y) * w[3] +
                 bfl(a3.z) * w[4] + bfh(a3.z) * w[5] + bfl(a3.w) * w[6] + bfh(a3.w) * w[7];
      float m0 = bfu(g0) + e0;
      float m1 = bfu(g1) + e1;
      float m2 = bfu(g2) + e2;
      float m3 = bfu(g3) + e3;
      acc += (m0 > 0.0f ? m0 : 0.0f) + (m1 > 0.0f ? m1 : 0.0f) +
             (m2 > 0.0f ? m2 : 0.0f) + (m3 > 0.0f ? m3 : 0.0f);
    }
    for (; i < deg; i++) {
      int s0 = P.ssrc[base + i];
      unsigned short g0 = P.hb[(size_t)s0 * 64 + d];
      uint4 a0 = *(const uint4*)&P.eas[(size_t)(base + i) * 8];
      float e0 = bed + bfl(a0.x) * w[0] + bfh(a0.x) * w[1] + bfl(a0.y) * w[2] + bfh(a0.y) * w[3] +
                 bfl(a0.z) * w[4] + bfh(a0.z) * w[5] + bfl(a0.w) * w[6] + bfh(a0.w) * w[7];
      float m0 = bfu(g0) + e0;
      acc += m0 > 0.0f ? m0 : 0.0f;
    }
    P.aggb[(size_t)v * 64 + d] = (unsigned short)f2bf(acc);
  } else {
    // ---- seg path: gsumb[s] = bf16(mean_{n in seg s} h[n]) ----
    int s = blk - EB;
    int ch = tid & 63, r = tid >> 6;
    int base = P.noff[s], c = P.ncnt[s];
    float acc = 0.0f;
    int i = r;
    for (; i + 12 < c; i += 16) {
      int n0 = P.nsorted[base + i];
      int n1 = P.nsorted[base + i + 4];
      int n2 = P.nsorted[base + i + 8];
      int n3 = P.nsorted[base + i + 12];
      acc += bfu(P.hb[(size_t)n0 * 64 + ch]) + bfu(P.hb[(size_t)n1 * 64 + ch]) +
             bfu(P.hb[(size_t)n2 * 64 + ch]) + bfu(P.hb[(size_t)n3 * 64 + ch]);
    }
    for (; i < c; i += 4) acc += bfu(P.hb[(size_t)P.nsorted[base + i] * 64 + ch]);
    red[tid] = acc;
    __syncthreads();
    if (r == 0) {
      float vsum = red[ch] + red[64 + ch] + red[128 + ch] + red[192 + ch];
      P.gsumb[s * 64 + ch] = (unsigned short)f2bf(vsum * P.cinv[s]);
    }
  }
}

// ---------------- wave-autonomous node kernel (MFMA, no barriers) ----------------
struct NodeArgs {
  const unsigned short* hb;
  const unsigned short* aggb;
  const unsigned short* gsumb;
  const int* nidx;
  const int* root;
  const int* tr;
  const float* eps[4];
  const short* wt1[4];
  const short* wt2[4];
  const float* b1[4];
  const float* b2[4];
  const float* ga[4];
  const float* bb[4];
  unsigned short* hbout;
};

__global__ __launch_bounds__(256, 4) void k_node(NodeArgs A) {
  __shared__ short sT[4][16 * LDH];  // per-wave band: GEMM1->GEMM2 transform + store staging
  int tid = threadIdx.x;
  int wv = tid >> 6;
  int lane = tid & 63;
  int m = lane & 15, q = lane >> 4;
  int gm = blockIdx.x * 64 + wv * 16 + m;
  bool valid = gm < NN;
  if (!valid) gm = 0;
  short* band = &sT[wv][0];

  int s = A.nidx[gm];
  int rv = A.root[s];
  int rt = A.tr[gm];

  // h chunks = this lane's A-fragment slices, loaded once, reused all 4 branches
  const unsigned short* hrow = &A.hb[(size_t)gm * 64];
  uint4 hq0 = *(const uint4*)&hrow[q * 8];
  uint4 hq1 = *(const uint4*)&hrow[32 + q * 8];
  float hv[8], hw[8];
  unp8(hq0, hv);
  unp8(hq1, hw);

  float hacc[4][4];
#pragma unroll
  for (int i = 0; i < 4; i++)
#pragma unroll
    for (int j = 0; j < 4; j++) hacc[i][j] = 0.0f;

#pragma unroll
  for (int b = 0; b < 4; b++) {
    float aeps = 1.0f + A.eps[b][0];
    uint4 o0, o1;
    if (b == 0) {
      const unsigned short* r0 = &A.aggb[(size_t)gm * 64];
      o0 = *(const uint4*)&r0[q * 8];
      o1 = *(const uint4*)&r0[32 + q * 8];
    } else if (b == 1) {
      const unsigned short* r0 = &A.hb[(size_t)rv * 64];
      o0 = *(const uint4*)&r0[q * 8];
      o1 = *(const uint4*)&r0[32 + q * 8];
    } else if (b == 2) {
      const unsigned short* r0 = &A.hb[(size_t)rt * 64];
      o0 = *(const uint4*)&r0[q * 8];
      o1 = *(const uint4*)&r0[32 + q * 8];
    } else {
      const unsigned short* r0 = &A.gsumb[(size_t)s * 64];
      o0 = *(const uint4*)&r0[q * 8];
      o1 = *(const uint4*)&r0[32 + q * 8];
    }
    float ov[8], ow[8];
    unp8(o0, ov);
    unp8(o1, ow);

    // A-fragments in registers, no LDS staging
    union { bf16x8 v; uint4 u; } a0u, a1u;
    a0u.u.x = pack2(aeps * hv[0] + ov[0], aeps * hv[1] + ov[1]);
    a0u.u.y = pack2(aeps * hv[2] + ov[2], aeps * hv[3] + ov[3]);
    a0u.u.z = pack2(aeps * hv[4] + ov[4], aeps * hv[5] + ov[5]);
    a0u.u.w = pack2(aeps * hv[6] + ov[6], aeps * hv[7] + ov[7]);
    a1u.u.x = pack2(aeps * hw[0] + ow[0], aeps * hw[1] + ow[1]);
    a1u.u.y = pack2(aeps * hw[2] + ow[2], aeps * hw[3] + ow[3]);
    a1u.u.z = pack2(aeps * hw[4] + ow[4], aeps * hw[5] + ow[5]);
    a1u.u.w = pack2(aeps * hw[6] + ow[6], aeps * hw[7] + ow[7]);

    const short* w1 = A.wt1[b];
    const short* w2 = A.wt2[b];
    const float* b1p = A.b1[b];
    const float* b2p = A.b2[b];

    // GEMM1: T = relu(U @ W1 + b1) -> band (wave-local)
#pragma unroll
    for (int t = 0; t < 4; t++) {
      int n = t * 16 + m;
      bf16x8 w0 = *(const bf16x8*)&w1[n * 64 + q * 8];
      bf16x8 wk = *(const bf16x8*)&w1[n * 64 + 32 + q * 8];
      float bv = b1p[n];
      f32x4 c = {bv, bv, bv, bv};
      c = __builtin_amdgcn_mfma_f32_16x16x32_bf16(a0u.v, w0, c, 0, 0, 0);
      c = __builtin_amdgcn_mfma_f32_16x16x32_bf16(a1u.v, wk, c, 0, 0, 0);
#pragma unroll
      for (int r = 0; r < 4; r++) {
        float v = c[r];
        v = v > 0.0f ? v : 0.0f;
        band[(q * 4 + r) * LDH + n] = f2bf(v);
      }
    }

    bf16x8 t0 = *(const bf16x8*)&band[m * LDH + q * 8];
    bf16x8 t1 = *(const bf16x8*)&band[m * LDH + 32 + q * 8];

    // GEMM2: V = T @ W2 + b2
    f32x4 c2[4];
#pragma unroll
    for (int t = 0; t < 4; t++) {
      int n = t * 16 + m;
      bf16x8 w0 = *(const bf16x8*)&w2[n * 64 + q * 8];
      bf16x8 wk = *(const bf16x8*)&w2[n * 64 + 32 + q * 8];
      float bv = b2p[n];
      f32x4 c = {bv, bv, bv, bv};
      c = __builtin_amdgcn_mfma_f32_16x16x32_bf16(t0, w0, c, 0, 0, 0);
      c = __builtin_amdgcn_mfma_f32_16x16x32_bf16(t1, wk, c, 0, 0, 0);
      c2[t] = c;
    }

    // LayerNorm per row (rows q*4+r; 16-lane quad groups hold all 64 cols)
    const float* ga = A.ga[b];
    const float* bbp = A.bb[b];
    float gav[4], bbv[4];
#pragma unroll
    for (int t = 0; t < 4; t++) {
      gav[t] = ga[t * 16 + m];
      bbv[t] = bbp[t * 16 + m];
    }
#pragma unroll
    for (int r = 0; r < 4; r++) {
      float s1 = c2[0][r] + c2[1][r] + c2[2][r] + c2[3][r];
      float s2 = c2[0][r] * c2[0][r] + c2[1][r] * c2[1][r] +
                 c2[2][r] * c2[2][r] + c2[3][r] * c2[3][r];
#pragma unroll
      for (int o = 1; o < 16; o <<= 1) {
        s1 += __shfl_xor(s1, o);
        s2 += __shfl_xor(s2, o);
      }
      float mu = s1 * (1.0f / 64.0f);
      float var = s2 * (1.0f / 64.0f) - mu * mu;
      float rr = rsqrtf(var + 1e-5f);
#pragma unroll
      for (int t = 0; t < 4; t++)
        hacc[r][t] += (c2[t][r] - mu) * rr * gav[t] + bbv[t];
    }
  }

  // epilogue: LDS roundtrip to coalesce bf16 stores (2x16B per lane)
#pragma unroll
  for (int r = 0; r < 4; r++)
#pragma unroll
    for (int t = 0; t < 4; t++)
      band[(q * 4 + r) * LDH + t * 16 + m] = f2bf(hacc[r][t]);
  if (valid) {
    uint4 v0 = *(const uint4*)&band[m * LDH + q * 8];
    uint4 v1 = *(const uint4*)&band[m * LDH + 32 + q * 8];
    unsigned short* orow = &A.hbout[(size_t)gm * 64];
    *(uint4*)&orow[q * 8] = v0;
    *(uint4*)&orow[32 + q * 8] = v1;
  }
}

// ---------------- fused final pooling + decoder ----------------
__global__ __launch_bounds__(256) void k_pool_out(const unsigned short* __restrict__ hb,
                                                  const int* __restrict__ nsorted,
                                                  const int* __restrict__ noff,
                                                  const int* __restrict__ ncnt,
                                                  const float* __restrict__ W,
                                                  const float* __restrict__ bjk,
                                                  float* __restrict__ out) {
  __shared__ float red[256];
  __shared__ float pr[64];
  int s = blockIdx.x, tid = threadIdx.x;
  int ch = tid & 63, r = tid >> 6;
  int base = noff[s], c = ncnt[s];
  float acc = 0.0f;
  int i = r;
  for (; i + 12 < c; i += 16) {
    int n0 = nsorted[base + i];
    int n1 = nsorted[base + i + 4];
    int n2 = nsorted[base + i + 8];
    int n3 = nsorted[base + i + 12];
    acc += bfu(hb[(size_t)n0 * 64 + ch]) + bfu(hb[(size_t)n1 * 64 + ch]) +
           bfu(hb[(size_t)n2 * 64 + ch]) + bfu(hb[(size_t)n3 * 64 + ch]);
  }
  for (; i < c; i += 4) acc += bfu(hb[(size_t)nsorted[base + i] * 64 + ch]);
  red[tid] = acc;
  __syncthreads();
  if (r == 0) pr[ch] = red[ch] + red[64 + ch] + red[128 + ch] + red[192 + ch];
  __syncthreads();
  if (tid < 64) {
    float o = bjk[tid];
#pragma unroll 8
    for (int k = 0; k < 64; k++) o += pr[k] * W[k * 64 + tid];
    out[s * 64 + tid] = o;
  }
}

extern "C" void kernel_launch(void* const* d_in, const int* in_sizes, int n_in,
                              void* d_out, int out_size, void* d_ws, size_t ws_size,
                              hipStream_t stream) {
  const float* x = (const float*)d_in[0];
  const float* edge_attr = (const float*)d_in[1];
  const int* edge_index = (const int*)d_in[2];
  const int* node_idx = (const int*)d_in[3];
  const int* root_idx = (const int*)d_in[4];
  const int* transpose_idx = (const int*)d_in[5];
  const float* W_init = (const float*)d_in[6];
  const float* b_init = (const float*)d_in[7];
  const float* lu_We = (const float*)d_in[8];
  const float* lu_be = (const float*)d_in[9];
  const float* eps_[4] = {(const float*)d_in[10], (const float*)d_in[17],
                          (const float*)d_in[24], (const float*)d_in[31]};
  const float* W1_[4] = {(const float*)d_in[11], (const float*)d_in[18],
                         (const float*)d_in[25], (const float*)d_in[32]};
  const float* b1_[4] = {(const float*)d_in[12], (const float*)d_in[19],
                         (const float*)d_in[26], (const float*)d_in[33]};
  const float* W2_[4] = {(const float*)d_in[13], (const float*)d_in[20],
                         (const float*)d_in[27], (const float*)d_in[34]};
  const float* b2_[4] = {(const float*)d_in[14], (const float*)d_in[21],
                         (const float*)d_in[28], (const float*)d_in[35]};
  const float* ga_[4] = {(const float*)d_in[15], (const float*)d_in[22],
                         (const float*)d_in[29], (const float*)d_in[36]};
  const float* bn_[4] = {(const float*)d_in[16], (const float*)d_in[23],
                         (const float*)d_in[30], (const float*)d_in[37]};
  const float* W_jk = (const float*)d_in[38];
  const float* b_jk = (const float*)d_in[39];

  // ---- workspace carve (~122 MB) ----
  char* p = (char*)d_ws;
  auto carve = [&](size_t bytes) -> char* {
    char* r = p;
    p += (bytes + 255) & ~(size_t)255;
    return r;
  };
  unsigned short* hb0 = (unsigned short*)carve((size_t)NN * DD * 2);   // 32 MB
  unsigned short* hb1 = (unsigned short*)carve((size_t)NN * DD * 2);   // 32 MB
  unsigned short* aggb = (unsigned short*)carve((size_t)NN * DD * 2);  // 32 MB
  unsigned short* gsumb = (unsigned short*)carve(SS * DD * 2);
  float* cinv = (float*)carve(SS * 4);
  short* wbt = (short*)carve(24 * 4096 * 2);
  int* ecnt = (int*)carve(NN * 4);
  int* eoff = (int*)carve(NN * 4);
  int* ecurs = (int*)carve(NN * 4);
  int* ebsum = (int*)carve(256 * 4);
  int* ssrc = (int*)carve((size_t)EE * 4);                             // 4 MB
  unsigned short* eas = (unsigned short*)carve((size_t)EE * FEE * 2);  // 16 MB
  int* ncnt = (int*)carve(SS * 4);
  int* noff = (int*)carve(SS * 4);
  int* ncurs = (int*)carve(SS * 4);
  int* nbsum = (int*)carve(256 * 4);
  int* nsorted = (int*)carve(NN * 4);

  const int* srcp = edge_index;
  const int* dstp = edge_index + EE;

  // ---- build CSRs (identical work every call; graph-capture safe) ----
  hipMemsetAsync(ecnt, 0, NN * 4, stream);
  hipMemsetAsync(ncnt, 0, SS * 4, stream);
  k_hist<<<(EE + 255) / 256, 256, 0, stream>>>(dstp, ecnt, EE);
  k_hist<<<(NN + 255) / 256, 256, 0, stream>>>(node_idx, ncnt, NN);
  k_scan1<<<SNB, 256, 0, stream>>>(ecnt, eoff, ecurs, ebsum, NN);
  k_scan2<<<1, 256, 0, stream>>>(ebsum, SNB);
  k_scan3<<<SNB, 256, 0, stream>>>(eoff, ecurs, ebsum, NN);
  k_scan1<<<1, 256, 0, stream>>>(ncnt, noff, ncurs, nbsum, SS);
  k_bucket_e<<<(EE + 255) / 256, 256, 0, stream>>>(srcp, dstp, edge_attr, ecurs, ssrc, eas);
  k_bucket_n<<<(NN + 255) / 256, 256, 0, stream>>>(node_idx, ncurs, nsorted);
  k_cinv<<<(SS + 255) / 256, 256, 0, stream>>>(ncnt, cinv);

  k_init<<<(NN * DD) / 256, 256, 0, stream>>>(x, W_init, b_init, hb0);

  WPrep P;
  for (int b = 0; b < 4; b++) {
    P.W[b * 2 + 0] = W1_[b];
    P.W[b * 2 + 1] = W2_[b];
  }
  k_wprep<<<(24 * 4096) / 256, 256, 0, stream>>>(P, wbt);

  unsigned short* hbc = hb0;
  unsigned short* hbn = hb1;
  for (int l = 0; l < NL; l++) {
    ProdArgs PR;
    PR.hb = hbc; PR.eas = eas; PR.ssrc = ssrc; PR.eoff = eoff; PR.ecnt = ecnt;
    PR.We = lu_We + (size_t)l * FEE * DD;
    PR.be = lu_be + l * DD;
    PR.aggb = aggb;
    PR.nsorted = nsorted; PR.noff = noff; PR.ncnt = ncnt; PR.cinv = cinv;
    PR.gsumb = gsumb;
    k_prod<<<EB + SS, 256, 0, stream>>>(PR);

    NodeArgs A;
    A.hb = hbc; A.aggb = aggb; A.gsumb = gsumb;
    A.nidx = node_idx; A.root = root_idx; A.tr = transpose_idx;
    for (int b = 0; b < 4; b++) {
      A.eps[b] = eps_[b] + l;
      A.wt1[b] = wbt + ((size_t)(b * 2 + 0) * NL + l) * 4096;
      A.wt2[b] = wbt + ((size_t)(b * 2 + 1) * NL + l) * 4096;
      A.b1[b] = b1_[b] + l * DD;
      A.b2[b] = b2_[b] + l * DD;
      A.ga[b] = ga_[b] + l * DD;
      A.bb[b] = bn_[b] + l * DD;
    }
    A.hbout = hbn;
    k_node<<<(NN + 63) / 64, 256, 0, stream>>>(A);
    unsigned short* tmpb = hbc; hbc = hbn; hbn = tmpb;
  }

  k_pool_out<<<SS, 256, 0, stream>>>(hbc, nsorted, noff, ncnt, W_jk, b_jk, (float*)d_out);
}

// Round 7
// 1202.945 us; speedup vs baseline: 2.1867x; 1.0943x over previous
//
#include <hip/hip_runtime.h>

#define NN 250000
#define EE 1000000
#define SS 1000
#define DD 64
#define FIN 16
#define FEE 8
#define NL 3
#define LDH 72  // band row stride (bf16 elems); 144B row -> 2-way bank alias (free)
#define SCHUNK 1024
#define SNB ((NN + SCHUNK - 1) / SCHUNK)  // 245

typedef __attribute__((ext_vector_type(8))) short bf16x8;
typedef __attribute__((ext_vector_type(4))) float f32x4;

static __device__ __forceinline__ short f2bf(float f) {
  union { float f; unsigned u; } v{f};
  unsigned r = (v.u + 0x7fffu + ((v.u >> 16) & 1u)) >> 16;  // RNE
  return (short)r;
}
static __device__ __forceinline__ float bfl(unsigned u) {
  union { unsigned u; float f; } v{u << 16};
  return v.f;
}
static __device__ __forceinline__ float bfh(unsigned u) {
  union { unsigned u; float f; } v{u & 0xffff0000u};
  return v.f;
}
static __device__ __forceinline__ float bfu(unsigned short u) {
  union { unsigned u; float f; } v{(unsigned)u << 16};
  return v.f;
}
static __device__ __forceinline__ unsigned pack2(float a, float b) {
  return (unsigned)(unsigned short)f2bf(a) | ((unsigned)(unsigned short)f2bf(b) << 16);
}
static __device__ __forceinline__ void unp8(uint4 v, float* o) {
  o[0] = bfl(v.x); o[1] = bfh(v.x); o[2] = bfl(v.y); o[3] = bfh(v.y);
  o[4] = bfl(v.z); o[5] = bfh(v.z); o[6] = bfl(v.w); o[7] = bfh(v.w);
}

// ---------------- histogram ----------------
__global__ __launch_bounds__(256) void k_hist(const int* __restrict__ idx,
                                              int* __restrict__ cnt, int n) {
  int i = blockIdx.x * 256 + threadIdx.x;
  if (i < n) atomicAdd(&cnt[idx[i]], 1);
}

// ---------------- block-local exclusive scan (chunk=1024) ----------------
__global__ __launch_bounds__(256) void k_scan1(const int* __restrict__ cntv,
                                               int* __restrict__ off,
                                               int* __restrict__ curs,
                                               int* __restrict__ bsums, int n) {
  __shared__ int ls[256];
  int b = blockIdx.x, t = threadIdx.x;
  int base = b * SCHUNK + t * 4;
  int v[4];
#pragma unroll
  for (int j = 0; j < 4; j++) v[j] = (base + j < n) ? cntv[base + j] : 0;
  int s4 = v[0] + v[1] + v[2] + v[3];
  ls[t] = s4;
  __syncthreads();
  for (int o = 1; o < 256; o <<= 1) {
    int x = (t >= o) ? ls[t - o] : 0;
    __syncthreads();
    ls[t] += x;
    __syncthreads();
  }
  int run = ls[t] - s4;
#pragma unroll
  for (int j = 0; j < 4; j++) {
    if (base + j < n) { off[base + j] = run; curs[base + j] = run; }
    run += v[j];
  }
  if (t == 255) bsums[b] = ls[255];
}

__global__ __launch_bounds__(256) void k_scan2(int* __restrict__ bsums, int nb) {
  __shared__ int ls[256];
  int t = threadIdx.x;
  int v = (t < nb) ? bsums[t] : 0;
  ls[t] = v;
  __syncthreads();
  for (int o = 1; o < 256; o <<= 1) {
    int x = (t >= o) ? ls[t - o] : 0;
    __syncthreads();
    ls[t] += x;
    __syncthreads();
  }
  if (t < nb) bsums[t] = ls[t] - v;  // exclusive
}

__global__ __launch_bounds__(256) void k_scan3(int* __restrict__ off,
                                               int* __restrict__ curs,
                                               const int* __restrict__ bsums, int n) {
  int b = blockIdx.x, t = threadIdx.x;
  int add = bsums[b];
  int base = b * SCHUNK + t * 4;
#pragma unroll
  for (int j = 0; j < 4; j++)
    if (base + j < n) { off[base + j] += add; curs[base + j] += add; }
}

// ---------------- bucket scatter: src + bf16 edge-attrs in CSR order ----------------
__global__ __launch_bounds__(256) void k_bucket_e(const int* __restrict__ src,
                                                  const int* __restrict__ dst,
                                                  const float* __restrict__ ea,
                                                  int* __restrict__ curs,
                                                  int* __restrict__ ssrc,
                                                  unsigned short* __restrict__ eas) {
  int e = blockIdx.x * 256 + threadIdx.x;
  if (e >= EE) return;
  int pos = atomicAdd(&curs[dst[e]], 1);
  ssrc[pos] = src[e];
  const float* a = &ea[(size_t)e * 8];
  uint4 p;
  p.x = pack2(a[0], a[1]);
  p.y = pack2(a[2], a[3]);
  p.z = pack2(a[4], a[5]);
  p.w = pack2(a[6], a[7]);
  *(uint4*)&eas[(size_t)pos * 8] = p;
}

__global__ __launch_bounds__(256) void k_bucket_n(const int* __restrict__ nidx,
                                                  int* __restrict__ curs,
                                                  int* __restrict__ nsorted) {
  int n = blockIdx.x * 256 + threadIdx.x;
  if (n >= NN) return;
  int pos = atomicAdd(&curs[nidx[n]], 1);
  nsorted[pos] = n;
}

__global__ __launch_bounds__(256) void k_cinv(const int* __restrict__ ncnt,
                                              float* __restrict__ cinv) {
  int s = blockIdx.x * 256 + threadIdx.x;
  if (s < SS) {
    float c = (float)ncnt[s];
    cinv[s] = 1.0f / (c < 1.0f ? 1.0f : c);
  }
}

// ---------------- init encoder: hb = bf16(x @ W_init + b) ----------------
__global__ __launch_bounds__(256) void k_init(const float* __restrict__ x,
                                              const float* __restrict__ W,
                                              const float* __restrict__ b,
                                              unsigned short* __restrict__ hb) {
  int gid = blockIdx.x * 256 + threadIdx.x;
  int n = gid >> 6, d = gid & 63;
  const float* xr = x + (size_t)n * FIN;
  float acc = b[d];
#pragma unroll
  for (int k = 0; k < FIN; k++) acc += xr[k] * W[k * DD + d];
  hb[gid] = (unsigned short)f2bf(acc);
}

// ---------------- weight prep: bf16 W^T ----------------
struct WPrep { const float* W[8]; };

__global__ __launch_bounds__(256) void k_wprep(WPrep P, short* __restrict__ wbt) {
  int gid = blockIdx.x * 256 + threadIdx.x;  // 24*4096
  int slot = gid >> 12;
  int e = gid & 4095;
  int n = e >> 6, k = e & 63;
  int bg = slot / NL, l = slot % NL;
  float v = P.W[bg][(size_t)l * 4096 + k * 64 + n];
  wbt[gid] = f2bf(v);
}

// ---------------- segment mean (bf16 out) ----------------
__global__ __launch_bounds__(256) void k_gmean(const unsigned short* __restrict__ hb,
                                               const int* __restrict__ nsorted,
                                               const int* __restrict__ noff,
                                               const int* __restrict__ ncnt,
                                               const float* __restrict__ cinv,
                                               unsigned short* __restrict__ gsumb) {
  __shared__ float red[256];
  int s = blockIdx.x;
  int tid = threadIdx.x;
  int ch = tid & 63, r = tid >> 6;
  int base = noff[s], c = ncnt[s];
  float acc = 0.0f;
  int i = r;
  for (; i + 12 < c; i += 16) {
    int n0 = nsorted[base + i];
    int n1 = nsorted[base + i + 4];
    int n2 = nsorted[base + i + 8];
    int n3 = nsorted[base + i + 12];
    acc += bfu(hb[(size_t)n0 * 64 + ch]) + bfu(hb[(size_t)n1 * 64 + ch]) +
           bfu(hb[(size_t)n2 * 64 + ch]) + bfu(hb[(size_t)n3 * 64 + ch]);
  }
  for (; i < c; i += 4) acc += bfu(hb[(size_t)nsorted[base + i] * 64 + ch]);
  red[tid] = acc;
  __syncthreads();
  if (r == 0) {
    float vsum = red[ch] + red[64 + ch] + red[128 + ch] + red[192 + ch];
    gsumb[s * 64 + ch] = (unsigned short)f2bf(vsum * cinv[s]);
  }
}

// ---------------- fused node kernel: edge-agg + 4x(MLP+LN), wave-autonomous ----------------
struct NodeArgs {
  const unsigned short* hb;
  const unsigned short* gsumb;
  const unsigned short* eas;
  const int* ssrc;
  const int* eoff;
  const int* ecnt;
  const float* We;
  const float* be;
  const int* nidx;
  const int* root;
  const int* tr;
  const float* eps[4];
  const short* wt1[4];
  const short* wt2[4];
  const float* b1[4];
  const float* b2[4];
  const float* ga[4];
  const float* bb[4];
  unsigned short* hbout;
};

__global__ __launch_bounds__(256, 4) void k_node(NodeArgs A) {
  __shared__ short sT[4][16 * LDH];  // per-wave band (DS ops are wave-in-order: no barriers)
  int tid = threadIdx.x;
  int wv = tid >> 6;
  int lane = tid & 63;
  int m = lane & 15, q = lane >> 4;
  int row0 = blockIdx.x * 64 + wv * 16;
  int gm = row0 + m;
  bool valid = gm < NN;
  if (!valid) gm = 0;
  short* band = &sT[wv][0];

  // ---- Phase E: edge aggregation for this wave's 16 rows (lane = channel) ----
  {
    int d = lane;
    float w[8];
#pragma unroll
    for (int k = 0; k < 8; k++) w[k] = A.We[k * 64 + d];
    float bed = A.be[d];
    for (int rr = 0; rr < 16; rr++) {
      int v = row0 + rr;
      if (v >= NN) v = 0;
      int base = A.eoff[v], deg = A.ecnt[v];
      float acc = 0.0f;
      int i = 0;
      for (; i + 4 <= deg; i += 4) {
        int s0 = A.ssrc[base + i + 0];
        int s1 = A.ssrc[base + i + 1];
        int s2 = A.ssrc[base + i + 2];
        int s3 = A.ssrc[base + i + 3];
        unsigned short g0 = A.hb[(size_t)s0 * 64 + d];
        unsigned short g1 = A.hb[(size_t)s1 * 64 + d];
        unsigned short g2 = A.hb[(size_t)s2 * 64 + d];
        unsigned short g3 = A.hb[(size_t)s3 * 64 + d];
        uint4 a0 = *(const uint4*)&A.eas[(size_t)(base + i + 0) * 8];
        uint4 a1 = *(const uint4*)&A.eas[(size_t)(base + i + 1) * 8];
        uint4 a2 = *(const uint4*)&A.eas[(size_t)(base + i + 2) * 8];
        uint4 a3 = *(const uint4*)&A.eas[(size_t)(base + i + 3) * 8];
        float e0 = bed + bfl(a0.x) * w[0] + bfh(a0.x) * w[1] + bfl(a0.y) * w[2] + bfh(a0.y) * w[3] +
                   bfl(a0.z) * w[4] + bfh(a0.z) * w[5] + bfl(a0.w) * w[6] + bfh(a0.w) * w[7];
        float e1 = bed + bfl(a1.x) * w[0] + bfh(a1.x) * w[1] + bfl(a1.y) * w[2] + bfh(a1.y) * w[3] +
                   bfl(a1.z) * w[4] + bfh(a1.z) * w[5] + bfl(a1.w) * w[6] + bfh(a1.w) * w[7];
        float e2 = bed + bfl(a2.x) * w[0] + bfh(a2.x) * w[1] + bfl(a2.y) * w[2] + bfh(a2.y) * w[3] +
                   bfl(a2.z) * w[4] + bfh(a2.z) * w[5] + bfl(a2.w) * w[6] + bfh(a2.w) * w[7];
        float e3 = bed + bfl(a3.x) * w[0] + bfh(a3.x) * w[1] + bfl(a3.y) * w[2] + bfh(a3.y) * w[3] +
                   bfl(a3.z) * w[4] + bfh(a3.z) * w[5] + bfl(a3.w) * w[6] + bfh(a3.w) * w[7];
        float m0 = bfu(g0) + e0;
        float m1 = bfu(g1) + e1;
        float m2 = bfu(g2) + e2;
        float m3 = bfu(g3) + e3;
        acc += (m0 > 0.0f ? m0 : 0.0f) + (m1 > 0.0f ? m1 : 0.0f) +
               (m2 > 0.0f ? m2 : 0.0f) + (m3 > 0.0f ? m3 : 0.0f);
      }
      for (; i < deg; i++) {
        int s0 = A.ssrc[base + i];
        unsigned short g0 = A.hb[(size_t)s0 * 64 + d];
        uint4 a0 = *(const uint4*)&A.eas[(size_t)(base + i) * 8];
        float e0 = bed + bfl(a0.x) * w[0] + bfh(a0.x) * w[1] + bfl(a0.y) * w[2] + bfh(a0.y) * w[3] +
                   bfl(a0.z) * w[4] + bfh(a0.z) * w[5] + bfl(a0.w) * w[6] + bfh(a0.w) * w[7];
        float m0 = bfu(g0) + e0;
        acc += m0 > 0.0f ? m0 : 0.0f;
      }
      band[rr * LDH + d] = f2bf(acc);  // agg row rr, channel d
    }
  }

  // ---- Phase M: 4 branches of MLP+LN (lane = (m,q) fragment role) ----
  int s = A.nidx[gm];
  int rv = A.root[s];
  int rt = A.tr[gm];

  const unsigned short* hrow = &A.hb[(size_t)gm * 64];
  uint4 hq0 = *(const uint4*)&hrow[q * 8];
  uint4 hq1 = *(const uint4*)&hrow[32 + q * 8];
  float hv[8], hw[8];
  unp8(hq0, hv);
  unp8(hq1, hw);

  float hacc[4][4];
#pragma unroll
  for (int i = 0; i < 4; i++)
#pragma unroll
    for (int j = 0; j < 4; j++) hacc[i][j] = 0.0f;

#pragma unroll
  for (int b = 0; b < 4; b++) {
    float aeps = 1.0f + A.eps[b][0];
    float ov[8], ow[8];
    if (b == 0) {
      // agg from wave-local band (reads complete before GEMM1's T-writes: DS in-order)
      uint4 o0 = *(const uint4*)&band[m * LDH + q * 8];
      uint4 o1 = *(const uint4*)&band[m * LDH + 32 + q * 8];
      unp8(o0, ov);
      unp8(o1, ow);
    } else {
      const unsigned short* r0 = (b == 1) ? &A.hb[(size_t)rv * 64]
                               : (b == 2) ? &A.hb[(size_t)rt * 64]
                                          : &A.gsumb[(size_t)s * 64];
      uint4 o0 = *(const uint4*)&r0[q * 8];
      uint4 o1 = *(const uint4*)&r0[32 + q * 8];
      unp8(o0, ov);
      unp8(o1, ow);
    }

    union { bf16x8 v; uint4 u; } a0u, a1u;
    a0u.u.x = pack2(aeps * hv[0] + ov[0], aeps * hv[1] + ov[1]);
    a0u.u.y = pack2(aeps * hv[2] + ov[2], aeps * hv[3] + ov[3]);
    a0u.u.z = pack2(aeps * hv[4] + ov[4], aeps * hv[5] + ov[5]);
    a0u.u.w = pack2(aeps * hv[6] + ov[6], aeps * hv[7] + ov[7]);
    a1u.u.x = pack2(aeps * hw[0] + ow[0], aeps * hw[1] + ow[1]);
    a1u.u.y = pack2(aeps * hw[2] + ow[2], aeps * hw[3] + ow[3]);
    a1u.u.z = pack2(aeps * hw[4] + ow[4], aeps * hw[5] + ow[5]);
    a1u.u.w = pack2(aeps * hw[6] + ow[6], aeps * hw[7] + ow[7]);

    const short* w1 = A.wt1[b];
    const short* w2 = A.wt2[b];
    const float* b1p = A.b1[b];
    const float* b2p = A.b2[b];

    // GEMM1: T = relu(U @ W1 + b1) -> band (wave-local)
#pragma unroll
    for (int t = 0; t < 4; t++) {
      int n = t * 16 + m;
      bf16x8 w0 = *(const bf16x8*)&w1[n * 64 + q * 8];
      bf16x8 wk = *(const bf16x8*)&w1[n * 64 + 32 + q * 8];
      float bv = b1p[n];
      f32x4 c = {bv, bv, bv, bv};
      c = __builtin_amdgcn_mfma_f32_16x16x32_bf16(a0u.v, w0, c, 0, 0, 0);
      c = __builtin_amdgcn_mfma_f32_16x16x32_bf16(a1u.v, wk, c, 0, 0, 0);
#pragma unroll
      for (int r = 0; r < 4; r++) {
        float v = c[r];
        v = v > 0.0f ? v : 0.0f;
        band[(q * 4 + r) * LDH + n] = f2bf(v);
      }
    }

    bf16x8 t0 = *(const bf16x8*)&band[m * LDH + q * 8];
    bf16x8 t1 = *(const bf16x8*)&band[m * LDH + 32 + q * 8];

    // GEMM2: V = T @ W2 + b2
    f32x4 c2[4];
#pragma unroll
    for (int t = 0; t < 4; t++) {
      int n = t * 16 + m;
      bf16x8 w0 = *(const bf16x8*)&w2[n * 64 + q * 8];
      bf16x8 wk = *(const bf16x8*)&w2[n * 64 + 32 + q * 8];
      float bv = b2p[n];
      f32x4 c = {bv, bv, bv, bv};
      c = __builtin_amdgcn_mfma_f32_16x16x32_bf16(t0, w0, c, 0, 0, 0);
      c = __builtin_amdgcn_mfma_f32_16x16x32_bf16(t1, wk, c, 0, 0, 0);
      c2[t] = c;
    }

    // LayerNorm per row
    const float* ga = A.ga[b];
    const float* bbp = A.bb[b];
    float gav[4], bbv[4];
#pragma unroll
    for (int t = 0; t < 4; t++) {
      gav[t] = ga[t * 16 + m];
      bbv[t] = bbp[t * 16 + m];
    }
#pragma unroll
    for (int r = 0; r < 4; r++) {
      float s1 = c2[0][r] + c2[1][r] + c2[2][r] + c2[3][r];
      float s2 = c2[0][r] * c2[0][r] + c2[1][r] * c2[1][r] +
                 c2[2][r] * c2[2][r] + c2[3][r] * c2[3][r];
#pragma unroll
      for (int o = 1; o < 16; o <<= 1) {
        s1 += __shfl_xor(s1, o);
        s2 += __shfl_xor(s2, o);
      }
      float mu = s1 * (1.0f / 64.0f);
      float var = s2 * (1.0f / 64.0f) - mu * mu;
      float rr = rsqrtf(var + 1e-5f);
#pragma unroll
      for (int t = 0; t < 4; t++)
        hacc[r][t] += (c2[t][r] - mu) * rr * gav[t] + bbv[t];
    }
  }

  // epilogue: LDS roundtrip to coalesce bf16 stores (2x16B per lane)
#pragma unroll
  for (int r = 0; r < 4; r++)
#pragma unroll
    for (int t = 0; t < 4; t++)
      band[(q * 4 + r) * LDH + t * 16 + m] = f2bf(hacc[r][t]);
  if (valid) {
    uint4 v0 = *(const uint4*)&band[m * LDH + q * 8];
    uint4 v1 = *(const uint4*)&band[m * LDH + 32 + q * 8];
    unsigned short* orow = &A.hbout[(size_t)gm * 64];
    *(uint4*)&orow[q * 8] = v0;
    *(uint4*)&orow[32 + q * 8] = v1;
  }
}

// ---------------- fused final pooling + decoder ----------------
__global__ __launch_bounds__(256) void k_pool_out(const unsigned short* __restrict__ hb,
                                                  const int* __restrict__ nsorted,
                                                  const int* __restrict__ noff,
                                                  const int* __restrict__ ncnt,
                                                  const float* __restrict__ W,
                                                  const float* __restrict__ bjk,
                                                  float* __restrict__ out) {
  __shared__ float red[256];
  __shared__ float pr[64];
  int s = blockIdx.x, tid = threadIdx.x;
  int ch = tid & 63, r = tid >> 6;
  int base = noff[s], c = ncnt[s];
  float acc = 0.0f;
  int i = r;
  for (; i + 12 < c; i += 16) {
    int n0 = nsorted[base + i];
    int n1 = nsorted[base + i + 4];
    int n2 = nsorted[base + i + 8];
    int n3 = nsorted[base + i + 12];
    acc += bfu(hb[(size_t)n0 * 64 + ch]) + bfu(hb[(size_t)n1 * 64 + ch]) +
           bfu(hb[(size_t)n2 * 64 + ch]) + bfu(hb[(size_t)n3 * 64 + ch]);
  }
  for (; i < c; i += 4) acc += bfu(hb[(size_t)nsorted[base + i] * 64 + ch]);
  red[tid] = acc;
  __syncthreads();
  if (r == 0) pr[ch] = red[ch] + red[64 + ch] + red[128 + ch] + red[192 + ch];
  __syncthreads();
  if (tid < 64) {
    float o = bjk[tid];
#pragma unroll 8
    for (int k = 0; k < 64; k++) o += pr[k] * W[k * 64 + tid];
    out[s * 64 + tid] = o;
  }
}

extern "C" void kernel_launch(void* const* d_in, const int* in_sizes, int n_in,
                              void* d_out, int out_size, void* d_ws, size_t ws_size,
                              hipStream_t stream) {
  const float* x = (const float*)d_in[0];
  const float* edge_attr = (const float*)d_in[1];
  const int* edge_index = (const int*)d_in[2];
  const int* node_idx = (const int*)d_in[3];
  const int* root_idx = (const int*)d_in[4];
  const int* transpose_idx = (const int*)d_in[5];
  const float* W_init = (const float*)d_in[6];
  const float* b_init = (const float*)d_in[7];
  const float* lu_We = (const float*)d_in[8];
  const float* lu_be = (const float*)d_in[9];
  const float* eps_[4] = {(const float*)d_in[10], (const float*)d_in[17],
                          (const float*)d_in[24], (const float*)d_in[31]};
  const float* W1_[4] = {(const float*)d_in[11], (const float*)d_in[18],
                         (const float*)d_in[25], (const float*)d_in[32]};
  const float* b1_[4] = {(const float*)d_in[12], (const float*)d_in[19],
                         (const float*)d_in[26], (const float*)d_in[33]};
  const float* W2_[4] = {(const float*)d_in[13], (const float*)d_in[20],
                         (const float*)d_in[27], (const float*)d_in[34]};
  const float* b2_[4] = {(const float*)d_in[14], (const float*)d_in[21],
                         (const float*)d_in[28], (const float*)d_in[35]};
  const float* ga_[4] = {(const float*)d_in[15], (const float*)d_in[22],
                         (const float*)d_in[29], (const float*)d_in[36]};
  const float* bn_[4] = {(const float*)d_in[16], (const float*)d_in[23],
                         (const float*)d_in[30], (const float*)d_in[37]};
  const float* W_jk = (const float*)d_in[38];
  const float* b_jk = (const float*)d_in[39];

  // ---- workspace carve (~90 MB) ----
  char* p = (char*)d_ws;
  auto carve = [&](size_t bytes) -> char* {
    char* r = p;
    p += (bytes + 255) & ~(size_t)255;
    return r;
  };
  unsigned short* hb0 = (unsigned short*)carve((size_t)NN * DD * 2);  // 32 MB
  unsigned short* hb1 = (unsigned short*)carve((size_t)NN * DD * 2);  // 32 MB
  unsigned short* gsumb = (unsigned short*)carve(SS * DD * 2);
  float* cinv = (float*)carve(SS * 4);
  short* wbt = (short*)carve(24 * 4096 * 2);
  int* ecnt = (int*)carve(NN * 4);
  int* eoff = (int*)carve(NN * 4);
  int* ecurs = (int*)carve(NN * 4);
  int* ebsum = (int*)carve(256 * 4);
  int* ssrc = (int*)carve((size_t)EE * 4);                             // 4 MB
  unsigned short* eas = (unsigned short*)carve((size_t)EE * FEE * 2);  // 16 MB
  int* ncnt = (int*)carve(SS * 4);
  int* noff = (int*)carve(SS * 4);
  int* ncurs = (int*)carve(SS * 4);
  int* nbsum = (int*)carve(256 * 4);
  int* nsorted = (int*)carve(NN * 4);

  const int* srcp = edge_index;
  const int* dstp = edge_index + EE;

  // ---- build CSRs (identical work every call; graph-capture safe) ----
  hipMemsetAsync(ecnt, 0, NN * 4, stream);
  hipMemsetAsync(ncnt, 0, SS * 4, stream);
  k_hist<<<(EE + 255) / 256, 256, 0, stream>>>(dstp, ecnt, EE);
  k_hist<<<(NN + 255) / 256, 256, 0, stream>>>(node_idx, ncnt, NN);
  k_scan1<<<SNB, 256, 0, stream>>>(ecnt, eoff, ecurs, ebsum, NN);
  k_scan2<<<1, 256, 0, stream>>>(ebsum, SNB);
  k_scan3<<<SNB, 256, 0, stream>>>(eoff, ecurs, ebsum, NN);
  k_scan1<<<1, 256, 0, stream>>>(ncnt, noff, ncurs, nbsum, SS);
  k_bucket_e<<<(EE + 255) / 256, 256, 0, stream>>>(srcp, dstp, edge_attr, ecurs, ssrc, eas);
  k_bucket_n<<<(NN + 255) / 256, 256, 0, stream>>>(node_idx, ncurs, nsorted);
  k_cinv<<<(SS + 255) / 256, 256, 0, stream>>>(ncnt, cinv);

  k_init<<<(NN * DD) / 256, 256, 0, stream>>>(x, W_init, b_init, hb0);

  WPrep P;
  for (int b = 0; b < 4; b++) {
    P.W[b * 2 + 0] = W1_[b];
    P.W[b * 2 + 1] = W2_[b];
  }
  k_wprep<<<(24 * 4096) / 256, 256, 0, stream>>>(P, wbt);

  unsigned short* hbc = hb0;
  unsigned short* hbn = hb1;
  for (int l = 0; l < NL; l++) {
    k_gmean<<<SS, 256, 0, stream>>>(hbc, nsorted, noff, ncnt, cinv, gsumb);

    NodeArgs A;
    A.hb = hbc; A.gsumb = gsumb;
    A.eas = eas; A.ssrc = ssrc; A.eoff = eoff; A.ecnt = ecnt;
    A.We = lu_We + (size_t)l * FEE * DD;
    A.be = lu_be + l * DD;
    A.nidx = node_idx; A.root = root_idx; A.tr = transpose_idx;
    for (int b = 0; b < 4; b++) {
      A.eps[b] = eps_[b] + l;
      A.wt1[b] = wbt + ((size_t)(b * 2 + 0) * NL + l) * 4096;
      A.wt2[b] = wbt + ((size_t)(b * 2 + 1) * NL + l) * 4096;
      A.b1[b] = b1_[b] + l * DD;
      A.b2[b] = b2_[b] + l * DD;
      A.ga[b] = ga_[b] + l * DD;
      A.bb[b] = bn_[b] + l * DD;
    }
    A.hbout = hbn;
    k_node<<<(NN + 63) / 64, 256, 0, stream>>>(A);
    unsigned short* tmpb = hbc; hbc = hbn; hbn = tmpb;
  }

  k_pool_out<<<SS, 256, 0, stream>>>(hbc, nsorted, noff, ncnt, W_jk, b_jk, (float*)d_out);
}